// Round 6
// baseline (1181.252 us; speedup 1.0000x reference)
//
#include <hip/hip_runtime.h>
#include <math.h>

static inline int ceil_div(int a, int b) { return (a + b - 1) / b; }

// ---------------------------------------------------------------------------
// Setup kernels
// ---------------------------------------------------------------------------

__global__ __launch_bounds__(256) void zero2(int* __restrict__ a, int* __restrict__ b,
                                             int n) {
    int i = blockIdx.x * 256 + threadIdx.x;
    if (i < n) { a[i] = 0; b[i] = 0; }
}

__global__ __launch_bounds__(256) void hist_kernel(const int* __restrict__ dst,
                                                   int* __restrict__ deg, int E) {
    int e = blockIdx.x * 256 + threadIdx.x;
    if (e < E) atomicAdd(&deg[dst[e]], 1);
}

__global__ __launch_bounds__(256) void scan_blocksum(const int* __restrict__ deg,
                                                     int* __restrict__ bsum, int n) {
    __shared__ int red[256];
    int t = threadIdx.x;
    int base = blockIdx.x * 2048 + t * 8;
    int s = 0;
    #pragma unroll
    for (int i = 0; i < 8; ++i) {
        int idx = base + i;
        if (idx < n) s += deg[idx];
    }
    red[t] = s;
    __syncthreads();
    #pragma unroll
    for (int off = 128; off >= 1; off >>= 1) {
        if (t < off) red[t] += red[t + off];
        __syncthreads();
    }
    if (t == 0) bsum[blockIdx.x] = red[0];
}

__global__ __launch_bounds__(256) void scan_tops(int* __restrict__ bsum, int nb) {
    __shared__ int sh[256];
    int t = threadIdx.x;
    int orig = (t < nb) ? bsum[t] : 0;
    sh[t] = orig;
    __syncthreads();
    for (int off = 1; off < 256; off <<= 1) {
        int add = (t >= off) ? sh[t - off] : 0;
        __syncthreads();
        sh[t] += add;
        __syncthreads();
    }
    if (t < nb) bsum[t] = sh[t] - orig;  // exclusive prefix
}

__global__ __launch_bounds__(256) void scan_final(const int* __restrict__ deg,
                                                  const int* __restrict__ bsum,
                                                  int* __restrict__ rowp,
                                                  float* __restrict__ invd,
                                                  int n, int E) {
    __shared__ int sh[256];
    int t = threadIdx.x;
    int base = blockIdx.x * 2048 + t * 8;
    int loc[8];
    int s = 0;
    #pragma unroll
    for (int i = 0; i < 8; ++i) {
        int idx = base + i;
        int d = (idx < n) ? deg[idx] : 0;
        loc[i] = d;
        s += d;
    }
    sh[t] = s;
    __syncthreads();
    for (int off = 1; off < 256; off <<= 1) {
        int add = (t >= off) ? sh[t - off] : 0;
        __syncthreads();
        sh[t] += add;
        __syncthreads();
    }
    int run = bsum[blockIdx.x] + (sh[t] - s);
    #pragma unroll
    for (int i = 0; i < 8; ++i) {
        int idx = base + i;
        if (idx < n) {
            rowp[idx] = run;
            int d = loc[i];
            run += d;
            invd[idx] = 1.0f / (float)(d > 1 ? d : 1);
        }
    }
    if (blockIdx.x == 0 && t == 0) rowp[n] = E;
}

__global__ __launch_bounds__(256) void scatter_idx(const int* __restrict__ dst,
                                                   const int* __restrict__ rowp,
                                                   int* __restrict__ fill,
                                                   int* __restrict__ ei, int E) {
    int e = blockIdx.x * 256 + threadIdx.x;
    if (e >= E) return;
    int d = dst[e];
    int pos = rowp[d] + atomicAdd(&fill[d], 1);
    ei[pos] = e;
}

// Deterministic intra-node edge order (matches segment_sum's edge-index order).
// RK4 @ T=3 amplifies fp32 sum-order noise to O(1): determinism & order =
// correctness. NEVER change accumulation grouping downstream.
__global__ __launch_bounds__(256) void sort_fill(const int* __restrict__ rowp,
                                                 int* __restrict__ ei,
                                                 const int* __restrict__ src,
                                                 const float* __restrict__ p,
                                                 int2* __restrict__ epk, int n) {
    int node = blockIdx.x * 256 + threadIdx.x;
    if (node >= n) return;
    int b = rowp[node], e = rowp[node + 1];
    for (int i = b + 1; i < e; ++i) {
        int key = ei[i];
        int j = i - 1;
        while (j >= b && ei[j] > key) { ei[j + 1] = ei[j]; --j; }
        ei[j + 1] = key;
    }
    for (int i = b; i < e; ++i) {
        int id = ei[i];
        epk[i] = make_int2(src[id], __float_as_int(p[id]));
    }
}

__global__ __launch_bounds__(256) void pack_all(
    const float* __restrict__ W1, const float* __restrict__ R1,
    const float* __restrict__ Wa, const float* __restrict__ Ra,
    const float* __restrict__ Wb, const float* __restrict__ Rb,
    const float* __restrict__ W2, const float* __restrict__ R2,
    float* __restrict__ Bc1, float* __restrict__ Bca,
    float* __restrict__ Bcb, float* __restrict__ Bc2) {
    int idx = blockIdx.x * 256 + threadIdx.x;
    const int S1 = 256 * 192, S2 = 192 * 64, S4 = 64 * 48;
    if (idx < S1) {
        int k = idx / 192, c = idx % 192;
        float v;
        if (c < 64)       v = W1[k * 64 + c];
        else if (c < 128) v = W1[256 * 64 + k * 64 + (c - 64)];
        else              v = R1[k * 64 + (c - 128)];
        Bc1[idx] = v;
        return;
    }
    idx -= S1;
    if (idx < S2) { Bca[idx] = (idx < 8192) ? Wa[idx] : Ra[idx - 8192]; return; }
    idx -= S2;
    if (idx < S2) { Bcb[idx] = (idx < 8192) ? Wb[idx] : Rb[idx - 8192]; return; }
    idx -= S2;
    if (idx < S4) {
        int k = idx / 48, c = idx % 48;
        float v;
        if (c < 16)      v = W2[k * 16 + c];
        else if (c < 32) v = W2[64 * 16 + k * 16 + (c - 16)];
        else             v = R2[k * 16 + (c - 32)];
        Bc2[idx] = v;
    }
}

// ---------------------------------------------------------------------------
// R6: XCD-aware channel-sliced edge aggregation.
// Default dispatch round-robins blockIdx across the 8 XCDs, so blockIdx%8 ~
// XCD id. Blocks with sub in {2q,2q+1} process ONLY channel quarter q (16 of
// 64 ch) -> per-XCD gather working set = 50000*16*4 = 3.2 MB < 4 MB L2 ->
// gather becomes L2-resident (was: every XCD gathering from all 12.8 MB,
// ~30% hit, L3-service-bound at ~3.7 TB/s per R4's finding).
// Per (node,channel) the edge loop / unroll / fmaf chains are byte-identical
// to v5 -> bitwise identical output; only (node,ch)->(block,lane) assignment
// changes. If the %8 mapping assumption fails, this is merely neutral.
// Layout: 4 lanes/node x float4; 64 nodes/block; grid = ceil(n/128)*8
// (tile of 128 nodes = 4 quarters x 2 node-halves).
// ---------------------------------------------------------------------------
__global__ __launch_bounds__(256) void edge_agg64_q(const float* __restrict__ x,
                                                    const int* __restrict__ rowp,
                                                    const int2* __restrict__ epk,
                                                    const float* __restrict__ invd,
                                                    float* __restrict__ agg, int n) {
    int sub = blockIdx.x & 7;
    int q = sub >> 1, hh = sub & 1;
    int node = (blockIdx.x >> 3) * 128 + hh * 64 + (threadIdx.x >> 2);
    if (node >= n) return;
    int c4 = q * 16 + ((threadIdx.x & 3) << 2);
    int e = rowp[node], eend = rowp[node + 1];
    float sx = 0.f, sy = 0.f, sz = 0.f, sw = 0.f;
    float px = 0.f, py = 0.f, pz = 0.f, pw = 0.f;
    for (; e + 4 <= eend; e += 4) {
        int2 q0 = epk[e], q1 = epk[e + 1], q2 = epk[e + 2], q3 = epk[e + 3];
        int s0 = q0.x, s1 = q1.x, s2 = q2.x, s3 = q3.x;
        float p0 = __int_as_float(q0.y), p1 = __int_as_float(q1.y);
        float p2 = __int_as_float(q2.y), p3 = __int_as_float(q3.y);
        float4 v0 = *reinterpret_cast<const float4*>(&x[(size_t)s0 * 64 + c4]);
        float4 v1 = *reinterpret_cast<const float4*>(&x[(size_t)s1 * 64 + c4]);
        float4 v2 = *reinterpret_cast<const float4*>(&x[(size_t)s2 * 64 + c4]);
        float4 v3 = *reinterpret_cast<const float4*>(&x[(size_t)s3 * 64 + c4]);
        sx += (v0.x + v1.x) + (v2.x + v3.x);
        sy += (v0.y + v1.y) + (v2.y + v3.y);
        sz += (v0.z + v1.z) + (v2.z + v3.z);
        sw += (v0.w + v1.w) + (v2.w + v3.w);
        px = fmaf(p0, v0.x, fmaf(p1, v1.x, fmaf(p2, v2.x, fmaf(p3, v3.x, px))));
        py = fmaf(p0, v0.y, fmaf(p1, v1.y, fmaf(p2, v2.y, fmaf(p3, v3.y, py))));
        pz = fmaf(p0, v0.z, fmaf(p1, v1.z, fmaf(p2, v2.z, fmaf(p3, v3.z, pz))));
        pw = fmaf(p0, v0.w, fmaf(p1, v1.w, fmaf(p2, v2.w, fmaf(p3, v3.w, pw))));
    }
    for (; e < eend; ++e) {
        int2 qe = epk[e];
        int s = qe.x;
        float pe = __int_as_float(qe.y);
        float4 v = *reinterpret_cast<const float4*>(&x[(size_t)s * 64 + c4]);
        sx += v.x; sy += v.y; sz += v.z; sw += v.w;
        px = fmaf(pe, v.x, px); py = fmaf(pe, v.y, py);
        pz = fmaf(pe, v.z, pz); pw = fmaf(pe, v.w, pw);
    }
    float w = invd[node];
    float4 a0 = make_float4((sx - px) * w, (sy - py) * w, (sz - pz) * w, (sw - pw) * w);
    float4 a1 = make_float4(px * w, py * w, pz * w, pw * w);
    *reinterpret_cast<float4*>(&agg[(size_t)node * 128 + c4]) = a0;
    *reinterpret_cast<float4*>(&agg[(size_t)node * 128 + 64 + c4]) = a1;
}

// ---------------------------------------------------------------------------
// Hidden GEMM v48 (R5 winner, verbatim): 64x64 tile, 128 threads, micro 4x8,
// LDS dbuf. Measured win vs 4x4/256t (866.5 total).
// ---------------------------------------------------------------------------
__global__ __launch_bounds__(128) void hidden_gemm_48(
    const float* __restrict__ agg, const float* __restrict__ in,
    const float* __restrict__ B, const float* __restrict__ bias,
    int n, int mode, float* __restrict__ u_out,
    const float* __restrict__ hbuf, const float* __restrict__ acc_in,
    float* __restrict__ acc_out, float* __restrict__ t_out,
    float c1, float c2, float c3) {
    __shared__ __align__(16) float As[2][16][68];
    __shared__ __align__(16) float Bs[2][16][68];
    const int t = threadIdx.x;            // 0..127
    const int row0 = blockIdx.x * 64;
    const int ty = t >> 3, tx = t & 7;    // 16x8 thread grid, micro 4x8
    const int arow = t >> 1, alk = (t & 1) << 3;   // A staging: 2 float4/thread
    const int bkk = t >> 3, bcl = (t & 7) << 3;    // B staging: 2 float4/thread

    float4 a0v = make_float4(0.f, 0.f, 0.f, 0.f);
    float4 a1v = make_float4(0.f, 0.f, 0.f, 0.f);
    {
        int r = row0 + arow;
        if (r < n) {
            a0v = *reinterpret_cast<const float4*>(&agg[(size_t)r * 128 + alk]);
            a1v = *reinterpret_cast<const float4*>(&agg[(size_t)r * 128 + alk + 4]);
        }
    }
    float4 b0v = *reinterpret_cast<const float4*>(&B[(size_t)bkk * 64 + bcl]);
    float4 b1v = *reinterpret_cast<const float4*>(&B[(size_t)bkk * 64 + bcl + 4]);
    As[0][alk + 0][arow] = a0v.x; As[0][alk + 1][arow] = a0v.y;
    As[0][alk + 2][arow] = a0v.z; As[0][alk + 3][arow] = a0v.w;
    As[0][alk + 4][arow] = a1v.x; As[0][alk + 5][arow] = a1v.y;
    As[0][alk + 6][arow] = a1v.z; As[0][alk + 7][arow] = a1v.w;
    *reinterpret_cast<float4*>(&Bs[0][bkk][bcl])     = b0v;
    *reinterpret_cast<float4*>(&Bs[0][bkk][bcl + 4]) = b1v;
    __syncthreads();

    float acc[4][8];
    #pragma unroll
    for (int i = 0; i < 4; ++i)
        #pragma unroll
        for (int j = 0; j < 8; ++j) acc[i][j] = 0.f;

    for (int kt = 0; kt < 12; ++kt) {
        const int cur = kt & 1;
        if (kt + 1 < 12) {
            int k0 = (kt + 1) << 4;
            int r = row0 + arow;
            int kk = k0 + alk;
            a0v = make_float4(0.f, 0.f, 0.f, 0.f);
            a1v = make_float4(0.f, 0.f, 0.f, 0.f);
            if (r < n) {
                if (kk < 128) {
                    a0v = *reinterpret_cast<const float4*>(&agg[(size_t)r * 128 + kk]);
                    a1v = *reinterpret_cast<const float4*>(&agg[(size_t)r * 128 + kk + 4]);
                } else {
                    a0v = *reinterpret_cast<const float4*>(&in[(size_t)r * 64 + (kk - 128)]);
                    a1v = *reinterpret_cast<const float4*>(&in[(size_t)r * 64 + (kk - 124)]);
                }
            }
            b0v = *reinterpret_cast<const float4*>(&B[(size_t)(k0 + bkk) * 64 + bcl]);
            b1v = *reinterpret_cast<const float4*>(&B[(size_t)(k0 + bkk) * 64 + bcl + 4]);
        }
        #pragma unroll
        for (int kk = 0; kk < 16; ++kk) {
            float4 a4 = *reinterpret_cast<const float4*>(&As[cur][kk][ty << 2]);
            float4 b40 = *reinterpret_cast<const float4*>(&Bs[cur][kk][tx << 3]);
            float4 b41 = *reinterpret_cast<const float4*>(&Bs[cur][kk][(tx << 3) + 4]);
            float aa[4] = {a4.x, a4.y, a4.z, a4.w};
            float bb[8] = {b40.x, b40.y, b40.z, b40.w, b41.x, b41.y, b41.z, b41.w};
            #pragma unroll
            for (int i = 0; i < 4; ++i)
                #pragma unroll
                for (int j = 0; j < 8; ++j)
                    acc[i][j] = fmaf(aa[i], bb[j], acc[i][j]);
        }
        if (kt + 1 < 12) {
            const int nx = cur ^ 1;
            As[nx][alk + 0][arow] = a0v.x; As[nx][alk + 1][arow] = a0v.y;
            As[nx][alk + 2][arow] = a0v.z; As[nx][alk + 3][arow] = a0v.w;
            As[nx][alk + 4][arow] = a1v.x; As[nx][alk + 5][arow] = a1v.y;
            As[nx][alk + 6][arow] = a1v.z; As[nx][alk + 7][arow] = a1v.w;
            *reinterpret_cast<float4*>(&Bs[nx][bkk][bcl])     = b0v;
            *reinterpret_cast<float4*>(&Bs[nx][bkk][bcl + 4]) = b1v;
        }
        __syncthreads();
    }

    float4 bia0 = *reinterpret_cast<const float4*>(&bias[tx << 3]);
    float4 bia1 = *reinterpret_cast<const float4*>(&bias[(tx << 3) + 4]);
    #pragma unroll
    for (int i = 0; i < 4; ++i) {
        int r = row0 + (ty << 2) + i;
        if (r >= n) continue;
        size_t idx = (size_t)r * 64 + (tx << 3);
        float4 v0 = make_float4(acc[i][0] + bia0.x, acc[i][1] + bia0.y,
                                acc[i][2] + bia0.z, acc[i][3] + bia0.w);
        float4 v1 = make_float4(acc[i][4] + bia1.x, acc[i][5] + bia1.y,
                                acc[i][6] + bia1.z, acc[i][7] + bia1.w);
        if (mode == 0) {
            *reinterpret_cast<float4*>(&u_out[idx])     = v0;
            *reinterpret_cast<float4*>(&u_out[idx + 4]) = v1;
        } else {
            float4 ai0 = make_float4(0.f, 0.f, 0.f, 0.f);
            float4 ai1 = make_float4(0.f, 0.f, 0.f, 0.f);
            if (acc_in) {
                ai0 = *reinterpret_cast<const float4*>(&acc_in[idx]);
                ai1 = *reinterpret_cast<const float4*>(&acc_in[idx + 4]);
            }
            float4 an0 = make_float4(ai0.x + c3 * v0.x, ai0.y + c3 * v0.y,
                                     ai0.z + c3 * v0.z, ai0.w + c3 * v0.w);
            float4 an1 = make_float4(ai1.x + c3 * v1.x, ai1.y + c3 * v1.y,
                                     ai1.z + c3 * v1.z, ai1.w + c3 * v1.w);
            *reinterpret_cast<float4*>(&acc_out[idx])     = an0;
            *reinterpret_cast<float4*>(&acc_out[idx + 4]) = an1;
            float4 hb0 = *reinterpret_cast<const float4*>(&hbuf[idx]);
            float4 hb1 = *reinterpret_cast<const float4*>(&hbuf[idx + 4]);
            float4 to0 = make_float4(hb0.x + c1 * v0.x + c2 * an0.x,
                                     hb0.y + c1 * v0.y + c2 * an0.y,
                                     hb0.z + c1 * v0.z + c2 * an0.z,
                                     hb0.w + c1 * v0.w + c2 * an0.w);
            float4 to1 = make_float4(hb1.x + c1 * v1.x + c2 * an1.x,
                                     hb1.y + c1 * v1.y + c2 * an1.y,
                                     hb1.z + c1 * v1.z + c2 * an1.z,
                                     hb1.w + c1 * v1.w + c2 * an1.w);
            *reinterpret_cast<float4*>(&t_out[idx])     = to0;
            *reinterpret_cast<float4*>(&t_out[idx + 4]) = to1;
        }
    }
}

// ---------------------------------------------------------------------------
// conv1 GEMM v5: 32-row x 192-col tile, 128 threads, micro 4x12 (~85% of its
// LDS-issue ceiling per r2 counters). Unchanged.
// ---------------------------------------------------------------------------
__global__ __launch_bounds__(128) void conv1_gemm_v5(const float* __restrict__ x,
                                                     const float* __restrict__ B,
                                                     int n, float* __restrict__ yz,
                                                     float* __restrict__ base,
                                                     const float* __restrict__ b1) {
    __shared__ __align__(16) float As[16][36];
    __shared__ __align__(16) float Bs[16][200];
    const int t = threadIdx.x;
    const int row0 = blockIdx.x * 32;
    const int ty = t >> 4, tx = t & 15;
    const int arow = t >> 2, alk = (t & 3) << 2;
    const int bkk0 = t >> 4, bcol = (t & 15) << 2;
    float acc[4][12];
    #pragma unroll
    for (int i = 0; i < 4; ++i)
        #pragma unroll
        for (int j = 0; j < 12; ++j) acc[i][j] = 0.f;

    for (int kt = 0; kt < 16; ++kt) {
        int k0 = kt << 4;
        {
            float4 av = make_float4(0.f, 0.f, 0.f, 0.f);
            int r = row0 + arow;
            if (r < n)
                av = *reinterpret_cast<const float4*>(&x[(size_t)r * 256 + k0 + alk]);
            As[alk + 0][arow] = av.x; As[alk + 1][arow] = av.y;
            As[alk + 2][arow] = av.z; As[alk + 3][arow] = av.w;
        }
        #pragma unroll
        for (int hh = 0; hh < 2; ++hh) {
            int kk = bkk0 + 8 * hh;
            const float* bp = &B[(size_t)(k0 + kk) * 192 + bcol];
            *reinterpret_cast<float4*>(&Bs[kk][bcol])       = *reinterpret_cast<const float4*>(bp);
            *reinterpret_cast<float4*>(&Bs[kk][bcol + 64])  = *reinterpret_cast<const float4*>(bp + 64);
            *reinterpret_cast<float4*>(&Bs[kk][bcol + 128]) = *reinterpret_cast<const float4*>(bp + 128);
        }
        __syncthreads();
        #pragma unroll
        for (int kk = 0; kk < 16; ++kk) {
            float4 a0 = *reinterpret_cast<const float4*>(&As[kk][ty << 2]);
            float4 b0 = *reinterpret_cast<const float4*>(&Bs[kk][tx << 2]);
            float4 b1q = *reinterpret_cast<const float4*>(&Bs[kk][(tx << 2) + 64]);
            float4 b2q = *reinterpret_cast<const float4*>(&Bs[kk][(tx << 2) + 128]);
            float aa[4] = {a0.x, a0.y, a0.z, a0.w};
            float bb[12] = {b0.x, b0.y, b0.z, b0.w, b1q.x, b1q.y, b1q.z, b1q.w,
                            b2q.x, b2q.y, b2q.z, b2q.w};
            #pragma unroll
            for (int i = 0; i < 4; ++i)
                #pragma unroll
                for (int j = 0; j < 12; ++j)
                    acc[i][j] = fmaf(aa[i], bb[j], acc[i][j]);
        }
        __syncthreads();
    }

    float4 bb4 = *reinterpret_cast<const float4*>(&b1[tx << 2]);
    #pragma unroll
    for (int i = 0; i < 4; ++i) {
        int r = row0 + (ty << 2) + i;
        if (r >= n) continue;
        float4 q0 = make_float4(acc[i][0], acc[i][1], acc[i][2], acc[i][3]);
        float4 q1 = make_float4(acc[i][4], acc[i][5], acc[i][6], acc[i][7]);
        float4 q2 = make_float4(acc[i][8] + bb4.x, acc[i][9] + bb4.y,
                                acc[i][10] + bb4.z, acc[i][11] + bb4.w);
        *reinterpret_cast<float4*>(&yz[(size_t)r * 128 + (tx << 2)]) = q0;
        *reinterpret_cast<float4*>(&yz[(size_t)r * 128 + 64 + (tx << 2)]) = q1;
        *reinterpret_cast<float4*>(&base[(size_t)r * 64 + (tx << 2)]) = q2;
    }
}

// ---------------------------------------------------------------------------
// R6: conv1 edge transform, XCD-aware 8-channel chunks.
// chunk k = blockIdx%8 -> output channels [8k, 8k+8); per-XCD working set =
// y chunk (1.6MB) + z chunk (1.6MB) = 3.2MB < 4MB L2. 1 lane/node (inner
// body identical to v8); 256 nodes/block; grid = ceil(n/256)*8.
// ---------------------------------------------------------------------------
__global__ __launch_bounds__(256) void edge_tf64_c8(const float* __restrict__ yz,
                                                    const int* __restrict__ rowp,
                                                    const int2* __restrict__ epk,
                                                    const float* __restrict__ invd,
                                                    const float* __restrict__ base,
                                                    float* __restrict__ out, int n) {
    int node = (blockIdx.x >> 3) * 256 + threadIdx.x;
    if (node >= n) return;
    int c8 = (blockIdx.x & 7) << 3;
    int e = rowp[node], eend = rowp[node + 1];
    float a[8] = {0.f, 0.f, 0.f, 0.f, 0.f, 0.f, 0.f, 0.f};
    for (; e + 2 <= eend; e += 2) {
        int2 q0 = epk[e], q1 = epk[e + 1];
        int s0 = q0.x, s1 = q1.x;
        float p0 = __int_as_float(q0.y), p1 = __int_as_float(q1.y);
        float4 y0a = *reinterpret_cast<const float4*>(&yz[(size_t)s0 * 128 + c8]);
        float4 y0b = *reinterpret_cast<const float4*>(&yz[(size_t)s0 * 128 + c8 + 4]);
        float4 z0a = *reinterpret_cast<const float4*>(&yz[(size_t)s0 * 128 + 64 + c8]);
        float4 z0b = *reinterpret_cast<const float4*>(&yz[(size_t)s0 * 128 + 64 + c8 + 4]);
        float4 y1a = *reinterpret_cast<const float4*>(&yz[(size_t)s1 * 128 + c8]);
        float4 y1b = *reinterpret_cast<const float4*>(&yz[(size_t)s1 * 128 + c8 + 4]);
        float4 z1a = *reinterpret_cast<const float4*>(&yz[(size_t)s1 * 128 + 64 + c8]);
        float4 z1b = *reinterpret_cast<const float4*>(&yz[(size_t)s1 * 128 + 64 + c8 + 4]);
        const float* ya0 = &y0a.x; const float* yb0 = &y0b.x;
        const float* za0 = &z0a.x; const float* zb0 = &z0b.x;
        const float* ya1 = &y1a.x; const float* yb1 = &y1b.x;
        const float* za1 = &z1a.x; const float* zb1 = &z1b.x;
        #pragma unroll
        for (int j = 0; j < 4; ++j) {
            a[j]     += fmaf(p0, za0[j] - ya0[j], ya0[j]) + fmaf(p1, za1[j] - ya1[j], ya1[j]);
            a[4 + j] += fmaf(p0, zb0[j] - yb0[j], yb0[j]) + fmaf(p1, zb1[j] - yb1[j], yb1[j]);
        }
    }
    for (; e < eend; ++e) {
        int2 q = epk[e];
        int s = q.x;
        float pe = __int_as_float(q.y);
        float4 ya = *reinterpret_cast<const float4*>(&yz[(size_t)s * 128 + c8]);
        float4 yb = *reinterpret_cast<const float4*>(&yz[(size_t)s * 128 + c8 + 4]);
        float4 za = *reinterpret_cast<const float4*>(&yz[(size_t)s * 128 + 64 + c8]);
        float4 zb = *reinterpret_cast<const float4*>(&yz[(size_t)s * 128 + 64 + c8 + 4]);
        const float* fy = &ya.x; const float* gy = &yb.x;
        const float* fz = &za.x; const float* gz = &zb.x;
        #pragma unroll
        for (int j = 0; j < 4; ++j) {
            a[j]     += fmaf(pe, fz[j] - fy[j], fy[j]);
            a[4 + j] += fmaf(pe, gz[j] - gy[j], gy[j]);
        }
    }
    float w = invd[node];
    size_t idx = (size_t)node * 64 + c8;
    float4 ba = *reinterpret_cast<const float4*>(&base[idx]);
    float4 bbv = *reinterpret_cast<const float4*>(&base[idx + 4]);
    float4 o0 = make_float4(tanhf(fmaf(a[0], w, ba.x)), tanhf(fmaf(a[1], w, ba.y)),
                            tanhf(fmaf(a[2], w, ba.z)), tanhf(fmaf(a[3], w, ba.w)));
    float4 o1 = make_float4(tanhf(fmaf(a[4], w, bbv.x)), tanhf(fmaf(a[5], w, bbv.y)),
                            tanhf(fmaf(a[6], w, bbv.z)), tanhf(fmaf(a[7], w, bbv.w)));
    *reinterpret_cast<float4*>(&out[idx]) = o0;
    *reinterpret_cast<float4*>(&out[idx + 4]) = o1;
}

__global__ __launch_bounds__(256) void edge_tf16_lsm(const float* __restrict__ yz,
                                                     const int* __restrict__ rowp,
                                                     const int2* __restrict__ epk,
                                                     const float* __restrict__ invd,
                                                     const float* __restrict__ base,
                                                     float* __restrict__ out, int n) {
    int gid = blockIdx.x * 256 + threadIdx.x;
    int node = gid >> 4;
    if (node >= n) return;
    int c = gid & 15;
    int e = rowp[node], eend = rowp[node + 1];
    float a = 0.f;
    for (; e + 4 <= eend; e += 4) {
        int2 q0 = epk[e], q1 = epk[e + 1], q2 = epk[e + 2], q3 = epk[e + 3];
        int s0 = q0.x, s1 = q1.x, s2 = q2.x, s3 = q3.x;
        float p0 = __int_as_float(q0.y), p1 = __int_as_float(q1.y);
        float p2 = __int_as_float(q2.y), p3 = __int_as_float(q3.y);
        float y0 = yz[(size_t)s0 * 32 + c],      z0 = yz[(size_t)s0 * 32 + 16 + c];
        float y1 = yz[(size_t)s1 * 32 + c],      z1 = yz[(size_t)s1 * 32 + 16 + c];
        float y2 = yz[(size_t)s2 * 32 + c],      z2 = yz[(size_t)s2 * 32 + 16 + c];
        float y3 = yz[(size_t)s3 * 32 + c],      z3 = yz[(size_t)s3 * 32 + 16 + c];
        a += fmaf(p0, z0 - y0, y0);
        a += fmaf(p1, z1 - y1, y1);
        a += fmaf(p2, z2 - y2, y2);
        a += fmaf(p3, z3 - y3, y3);
    }
    for (; e < eend; ++e) {
        int2 q = epk[e];
        int s = q.x; float pe = __int_as_float(q.y);
        float y = yz[(size_t)s * 32 + c], z = yz[(size_t)s * 32 + 16 + c];
        a += fmaf(pe, z - y, y);
    }
    float o = tanhf(a * invd[node] + base[(size_t)node * 16 + c]);
    float m = o;
    #pragma unroll
    for (int off = 8; off >= 1; off >>= 1) m = fmaxf(m, __shfl_xor(m, off, 16));
    float ex = expf(o - m);
    float s = ex;
    #pragma unroll
    for (int off = 8; off >= 1; off >>= 1) s += __shfl_xor(s, off, 16);
    out[(size_t)node * 16 + c] = (o - m) - logf(s);
}

// ---------------------------------------------------------------------------
// conv2 GEMM (K=64, M=48)
// ---------------------------------------------------------------------------
__global__ __launch_bounds__(256) void gemm_tiled(
    const float* __restrict__ A0, int lda0, int K0,
    const float* __restrict__ A1, int lda1,
    const float* __restrict__ B,
    int n, int K, int M,
    float* __restrict__ out0, int w0, const float* __restrict__ bias0,
    float* __restrict__ out1, int w1, const float* __restrict__ bias1,
    int split) {
    __shared__ __align__(16) float As[16][68];
    __shared__ __align__(16) float Bs[16][68];
    const int t = threadIdx.x;
    const int row0 = blockIdx.x * 64;
    const int col0 = blockIdx.y * 64;
    const int ty = t >> 4, tx = t & 15;
    const int lrow = t >> 2, lk = (t & 3) << 2;
    const int bkk = t >> 4, bcol = (t & 15) << 2;
    float acc[4][4];
    #pragma unroll
    for (int i = 0; i < 4; ++i)
        #pragma unroll
        for (int j = 0; j < 4; ++j) acc[i][j] = 0.f;

    for (int k0 = 0; k0 < K; k0 += 16) {
        float4 av = make_float4(0.f, 0.f, 0.f, 0.f);
        {
            int r = row0 + lrow;
            if (r < n) {
                int kk = k0 + lk;
                const float* src = (kk < K0)
                    ? (A0 + (size_t)r * lda0 + kk)
                    : (A1 + (size_t)r * lda1 + (kk - K0));
                av = *reinterpret_cast<const float4*>(src);
            }
        }
        float4 bv = make_float4(0.f, 0.f, 0.f, 0.f);
        {
            int c = col0 + bcol;
            int kk = k0 + bkk;
            if (c < M) bv = *reinterpret_cast<const float4*>(B + (size_t)kk * M + c);
        }
        As[lk + 0][lrow] = av.x; As[lk + 1][lrow] = av.y;
        As[lk + 2][lrow] = av.z; As[lk + 3][lrow] = av.w;
        *reinterpret_cast<float4*>(&Bs[bkk][bcol]) = bv;
        __syncthreads();
        #pragma unroll
        for (int kk = 0; kk < 16; ++kk) {
            float4 a4 = *reinterpret_cast<const float4*>(&As[kk][ty << 2]);
            float4 b4 = *reinterpret_cast<const float4*>(&Bs[kk][tx << 2]);
            float aa[4] = {a4.x, a4.y, a4.z, a4.w};
            float bb[4] = {b4.x, b4.y, b4.z, b4.w};
            #pragma unroll
            for (int i = 0; i < 4; ++i)
                #pragma unroll
                for (int j = 0; j < 4; ++j)
                    acc[i][j] = fmaf(aa[i], bb[j], acc[i][j]);
        }
        __syncthreads();
    }

    #pragma unroll
    for (int i = 0; i < 4; ++i) {
        int r = row0 + (ty << 2) + i;
        if (r >= n) continue;
        #pragma unroll
        for (int j = 0; j < 4; ++j) {
            int c = col0 + (tx << 2) + j;
            if (c >= M) continue;
            float v = acc[i][j];
            if (c < split) {
                if (bias0) v += bias0[c];
                out0[(size_t)r * w0 + c] = v;
            } else {
                int cc = c - split;
                if (bias1) v += bias1[cc];
                out1[(size_t)r * w1 + cc] = v;
            }
        }
    }
}

// ---------------------------------------------------------------------------
// Host-side launcher
// ---------------------------------------------------------------------------

static void hidden_conv(hipStream_t stream, const float* in, float* agg,
                        const int* rowp, const int2* epk,
                        const float* invd, const float* Bc, const float* bias, int n,
                        int mode, float* u_out,
                        const float* h, const float* acc_in, float* acc_out,
                        float* t_out, float c1, float c2, float c3) {
    edge_agg64_q<<<ceil_div(n, 128) * 8, 256, 0, stream>>>(in, rowp, epk, invd,
                                                           agg, n);
    hidden_gemm_48<<<ceil_div(n, 64), 128, 0, stream>>>(agg, in, Bc, bias, n, mode,
                                                        u_out, h, acc_in, acc_out,
                                                        t_out, c1, c2, c3);
}

extern "C" void kernel_launch(void* const* d_in, const int* in_sizes, int n_in,
                              void* d_out, int out_size, void* d_ws, size_t ws_size,
                              hipStream_t stream) {
    const float* x  = (const float*)d_in[0];
    const float* pE = (const float*)d_in[1];
    const int*   sr = (const int*)d_in[2];
    const int*   ds = (const int*)d_in[3];
    const float* W1 = (const float*)d_in[4];
    const float* R1 = (const float*)d_in[5];
    const float* b1 = (const float*)d_in[6];
    const float* Wa = (const float*)d_in[7];
    const float* Ra = (const float*)d_in[8];
    const float* ba = (const float*)d_in[9];
    const float* Wb = (const float*)d_in[10];
    const float* Rb = (const float*)d_in[11];
    const float* bb = (const float*)d_in[12];
    const float* W2 = (const float*)d_in[13];
    const float* R2 = (const float*)d_in[14];
    const float* b2 = (const float*)d_in[15];
    const int n = in_sizes[0] / 256;
    const int E = in_sizes[2];
    float* out = (float*)d_out;

    char* w = (char*)d_ws;
    auto alloc = [&](size_t bytes) -> void* {
        void* ptr = (void*)w;
        w += (bytes + 255) & ~(size_t)255;
        return ptr;
    };
    int nscan = ceil_div(n, 2048);
    int*   deg  = (int*)alloc((size_t)n * 4);
    int*   fill = (int*)alloc((size_t)n * 4);
    int*   rowp = (int*)alloc((size_t)(n + 1) * 4);
    float* invd = (float*)alloc((size_t)n * 4);
    int*   bsum = (int*)alloc((size_t)256 * 4);
    int*   ei   = (int*)alloc((size_t)E * 4);
    int2*  epk  = (int2*)alloc((size_t)E * 8);
    float* Bc1  = (float*)alloc((size_t)256 * 192 * 4);
    float* Bca  = (float*)alloc((size_t)192 * 64 * 4);
    float* Bcb  = (float*)alloc((size_t)192 * 64 * 4);
    float* Bc2  = (float*)alloc((size_t)64 * 48 * 4);
    float* big0 = (float*)alloc((size_t)n * 128 * 4);  // yz / agg buffer
    float* big1 = (float*)alloc((size_t)n * 64 * 4);   // base buffer
    float* h    = (float*)alloc((size_t)n * 64 * 4);
    float* u    = (float*)alloc((size_t)n * 64 * 4);
    float* tb   = (float*)alloc((size_t)n * 64 * 4);
    float* acc  = (float*)alloc((size_t)n * 64 * 4);

    const int PACK_TOTAL = 256 * 192 + 2 * 192 * 64 + 64 * 48;

    zero2<<<ceil_div(n, 256), 256, 0, stream>>>(deg, fill, n);
    pack_all<<<ceil_div(PACK_TOTAL, 256), 256, 0, stream>>>(W1, R1, Wa, Ra, Wb, Rb,
                                                            W2, R2, Bc1, Bca, Bcb, Bc2);
    hist_kernel<<<ceil_div(E, 256), 256, 0, stream>>>(ds, deg, E);
    scan_blocksum<<<nscan, 256, 0, stream>>>(deg, bsum, n);
    scan_tops<<<1, 256, 0, stream>>>(bsum, nscan);
    scan_final<<<nscan, 256, 0, stream>>>(deg, bsum, rowp, invd, n, E);
    scatter_idx<<<ceil_div(E, 256), 256, 0, stream>>>(ds, rowp, fill, ei, E);
    sort_fill<<<ceil_div(n, 256), 256, 0, stream>>>(rowp, ei, sr, pE, epk, n);

    // conv1: x @ [W1_0|W1_1|R1] -> yz(big0), base(big1)+b1; then edge transform
    conv1_gemm_v5<<<ceil_div(n, 32), 128, 0, stream>>>(x, Bc1, n, big0, big1, b1);
    edge_tf64_c8<<<ceil_div(n, 256) * 8, 256, 0, stream>>>(big0, rowp, epk, invd,
                                                           big1, h, n);

    // RK4 over f(y) = conv_b(conv_a(y)), T=3
    // k1
    hidden_conv(stream, h, big0, rowp, epk, invd, Bca, ba, n, 0, u,
                nullptr, nullptr, nullptr, nullptr, 0.f, 0.f, 0.f);
    hidden_conv(stream, u, big0, rowp, epk, invd, Bcb, bb, n, 1, nullptr,
                h, nullptr, acc, tb, 1.5f, 0.f, 1.f);
    // k2
    hidden_conv(stream, tb, big0, rowp, epk, invd, Bca, ba, n, 0, u,
                nullptr, nullptr, nullptr, nullptr, 0.f, 0.f, 0.f);
    hidden_conv(stream, u, big0, rowp, epk, invd, Bcb, bb, n, 1, nullptr,
                h, acc, acc, tb, 1.5f, 0.f, 2.f);
    // k3
    hidden_conv(stream, tb, big0, rowp, epk, invd, Bca, ba, n, 0, u,
                nullptr, nullptr, nullptr, nullptr, 0.f, 0.f, 0.f);
    hidden_conv(stream, u, big0, rowp, epk, invd, Bcb, bb, n, 1, nullptr,
                h, acc, acc, tb, 3.f, 0.f, 2.f);
    // k4: t_out becomes h_new = h + 0.5*(k1+2k2+2k3+k4)
    hidden_conv(stream, tb, big0, rowp, epk, invd, Bca, ba, n, 0, u,
                nullptr, nullptr, nullptr, nullptr, 0.f, 0.f, 0.f);
    hidden_conv(stream, u, big0, rowp, epk, invd, Bcb, bb, n, 1, nullptr,
                h, acc, acc, tb, 0.f, 0.5f, 1.f);

    // conv2: h_new @ [W2_0|W2_1|R2] -> yz2(big0,w=32), base2(big1,w=16)+b2
    gemm_tiled<<<dim3(ceil_div(n, 64), 1), 256, 0, stream>>>(
        tb, 64, 64, nullptr, 0, Bc2, n, 64, 48,
        big0, 32, nullptr, big1, 16, b2, 32);
    edge_tf16_lsm<<<ceil_div(n * 16, 256), 256, 0, stream>>>(big0, rowp, epk, invd,
                                                             big1, out, n);
}

// Round 7
// 951.329 us; speedup vs baseline: 1.2417x; 1.2417x over previous
//
#include <hip/hip_runtime.h>
#include <math.h>

static inline int ceil_div(int a, int b) { return (a + b - 1) / b; }

// ---------------------------------------------------------------------------
// Setup kernels
// ---------------------------------------------------------------------------

__global__ __launch_bounds__(256) void zero2(int* __restrict__ a, int* __restrict__ b,
                                             int n) {
    int i = blockIdx.x * 256 + threadIdx.x;
    if (i < n) { a[i] = 0; b[i] = 0; }
}

__global__ __launch_bounds__(256) void hist_kernel(const int* __restrict__ dst,
                                                   int* __restrict__ deg, int E) {
    int e = blockIdx.x * 256 + threadIdx.x;
    if (e < E) atomicAdd(&deg[dst[e]], 1);
}

__global__ __launch_bounds__(256) void scan_blocksum(const int* __restrict__ deg,
                                                     int* __restrict__ bsum, int n) {
    __shared__ int red[256];
    int t = threadIdx.x;
    int base = blockIdx.x * 2048 + t * 8;
    int s = 0;
    #pragma unroll
    for (int i = 0; i < 8; ++i) {
        int idx = base + i;
        if (idx < n) s += deg[idx];
    }
    red[t] = s;
    __syncthreads();
    #pragma unroll
    for (int off = 128; off >= 1; off >>= 1) {
        if (t < off) red[t] += red[t + off];
        __syncthreads();
    }
    if (t == 0) bsum[blockIdx.x] = red[0];
}

__global__ __launch_bounds__(256) void scan_tops(int* __restrict__ bsum, int nb) {
    __shared__ int sh[256];
    int t = threadIdx.x;
    int orig = (t < nb) ? bsum[t] : 0;
    sh[t] = orig;
    __syncthreads();
    for (int off = 1; off < 256; off <<= 1) {
        int add = (t >= off) ? sh[t - off] : 0;
        __syncthreads();
        sh[t] += add;
        __syncthreads();
    }
    if (t < nb) bsum[t] = sh[t] - orig;  // exclusive prefix
}

__global__ __launch_bounds__(256) void scan_final(const int* __restrict__ deg,
                                                  const int* __restrict__ bsum,
                                                  int* __restrict__ rowp,
                                                  float* __restrict__ invd,
                                                  int n, int E) {
    __shared__ int sh[256];
    int t = threadIdx.x;
    int base = blockIdx.x * 2048 + t * 8;
    int loc[8];
    int s = 0;
    #pragma unroll
    for (int i = 0; i < 8; ++i) {
        int idx = base + i;
        int d = (idx < n) ? deg[idx] : 0;
        loc[i] = d;
        s += d;
    }
    sh[t] = s;
    __syncthreads();
    for (int off = 1; off < 256; off <<= 1) {
        int add = (t >= off) ? sh[t - off] : 0;
        __syncthreads();
        sh[t] += add;
        __syncthreads();
    }
    int run = bsum[blockIdx.x] + (sh[t] - s);
    #pragma unroll
    for (int i = 0; i < 8; ++i) {
        int idx = base + i;
        if (idx < n) {
            rowp[idx] = run;
            int d = loc[i];
            run += d;
            invd[idx] = 1.0f / (float)(d > 1 ? d : 1);
        }
    }
    if (blockIdx.x == 0 && t == 0) rowp[n] = E;
}

__global__ __launch_bounds__(256) void scatter_idx(const int* __restrict__ dst,
                                                   const int* __restrict__ rowp,
                                                   int* __restrict__ fill,
                                                   int* __restrict__ ei, int E) {
    int e = blockIdx.x * 256 + threadIdx.x;
    if (e >= E) return;
    int d = dst[e];
    int pos = rowp[d] + atomicAdd(&fill[d], 1);
    ei[pos] = e;
}

// Deterministic intra-node edge order (matches segment_sum's edge-index order).
// RK4 @ T=3 amplifies fp32 sum-order noise to O(1): determinism & order =
// correctness. NEVER change accumulation grouping downstream.
__global__ __launch_bounds__(256) void sort_fill(const int* __restrict__ rowp,
                                                 int* __restrict__ ei,
                                                 const int* __restrict__ src,
                                                 const float* __restrict__ p,
                                                 int2* __restrict__ epk, int n) {
    int node = blockIdx.x * 256 + threadIdx.x;
    if (node >= n) return;
    int b = rowp[node], e = rowp[node + 1];
    for (int i = b + 1; i < e; ++i) {
        int key = ei[i];
        int j = i - 1;
        while (j >= b && ei[j] > key) { ei[j + 1] = ei[j]; --j; }
        ei[j + 1] = key;
    }
    for (int i = b; i < e; ++i) {
        int id = ei[i];
        epk[i] = make_int2(src[id], __float_as_int(p[id]));
    }
}

__global__ __launch_bounds__(256) void pack_all(
    const float* __restrict__ W1, const float* __restrict__ R1,
    const float* __restrict__ Wa, const float* __restrict__ Ra,
    const float* __restrict__ Wb, const float* __restrict__ Rb,
    const float* __restrict__ W2, const float* __restrict__ R2,
    float* __restrict__ Bc1, float* __restrict__ Bca,
    float* __restrict__ Bcb, float* __restrict__ Bc2) {
    int idx = blockIdx.x * 256 + threadIdx.x;
    const int S1 = 256 * 192, S2 = 192 * 64, S4 = 64 * 48;
    if (idx < S1) {
        int k = idx / 192, c = idx % 192;
        float v;
        if (c < 64)       v = W1[k * 64 + c];
        else if (c < 128) v = W1[256 * 64 + k * 64 + (c - 64)];
        else              v = R1[k * 64 + (c - 128)];
        Bc1[idx] = v;
        return;
    }
    idx -= S1;
    if (idx < S2) { Bca[idx] = (idx < 8192) ? Wa[idx] : Ra[idx - 8192]; return; }
    idx -= S2;
    if (idx < S2) { Bcb[idx] = (idx < 8192) ? Wb[idx] : Rb[idx - 8192]; return; }
    idx -= S2;
    if (idx < S4) {
        int k = idx / 48, c = idx % 48;
        float v;
        if (c < 16)      v = W2[k * 16 + c];
        else if (c < 32) v = W2[64 * 16 + k * 16 + (c - 16)];
        else             v = R2[k * 16 + (c - 32)];
        Bc2[idx] = v;
    }
}

// ---------------------------------------------------------------------------
// Edge aggregation (hidden convs): 16 lanes/node x float4 — R5 form.
// 16 lanes cover a node's full 64-ch row (256B = 2 lines, fully used).
// R6 lesson: any slicing below 128B/source-row multiplies line traffic 2-4x.
// ---------------------------------------------------------------------------
__global__ __launch_bounds__(256) void edge_agg64_v5(const float* __restrict__ x,
                                                     const int* __restrict__ rowp,
                                                     const int2* __restrict__ epk,
                                                     const float* __restrict__ invd,
                                                     float* __restrict__ agg, int n) {
    int gid = blockIdx.x * 256 + threadIdx.x;
    int node = gid >> 4;
    if (node >= n) return;
    int c4 = (gid & 15) << 2;
    int e = rowp[node], eend = rowp[node + 1];
    float sx = 0.f, sy = 0.f, sz = 0.f, sw = 0.f;
    float px = 0.f, py = 0.f, pz = 0.f, pw = 0.f;
    for (; e + 4 <= eend; e += 4) {
        int2 q0 = epk[e], q1 = epk[e + 1], q2 = epk[e + 2], q3 = epk[e + 3];
        int s0 = q0.x, s1 = q1.x, s2 = q2.x, s3 = q3.x;
        float p0 = __int_as_float(q0.y), p1 = __int_as_float(q1.y);
        float p2 = __int_as_float(q2.y), p3 = __int_as_float(q3.y);
        float4 v0 = *reinterpret_cast<const float4*>(&x[(size_t)s0 * 64 + c4]);
        float4 v1 = *reinterpret_cast<const float4*>(&x[(size_t)s1 * 64 + c4]);
        float4 v2 = *reinterpret_cast<const float4*>(&x[(size_t)s2 * 64 + c4]);
        float4 v3 = *reinterpret_cast<const float4*>(&x[(size_t)s3 * 64 + c4]);
        sx += (v0.x + v1.x) + (v2.x + v3.x);
        sy += (v0.y + v1.y) + (v2.y + v3.y);
        sz += (v0.z + v1.z) + (v2.z + v3.z);
        sw += (v0.w + v1.w) + (v2.w + v3.w);
        px = fmaf(p0, v0.x, fmaf(p1, v1.x, fmaf(p2, v2.x, fmaf(p3, v3.x, px))));
        py = fmaf(p0, v0.y, fmaf(p1, v1.y, fmaf(p2, v2.y, fmaf(p3, v3.y, py))));
        pz = fmaf(p0, v0.z, fmaf(p1, v1.z, fmaf(p2, v2.z, fmaf(p3, v3.z, pz))));
        pw = fmaf(p0, v0.w, fmaf(p1, v1.w, fmaf(p2, v2.w, fmaf(p3, v3.w, pw))));
    }
    for (; e < eend; ++e) {
        int2 q = epk[e];
        int s = q.x;
        float pe = __int_as_float(q.y);
        float4 v = *reinterpret_cast<const float4*>(&x[(size_t)s * 64 + c4]);
        sx += v.x; sy += v.y; sz += v.z; sw += v.w;
        px = fmaf(pe, v.x, px); py = fmaf(pe, v.y, py);
        pz = fmaf(pe, v.z, pz); pw = fmaf(pe, v.w, pw);
    }
    float w = invd[node];
    float4 a0 = make_float4((sx - px) * w, (sy - py) * w, (sz - pz) * w, (sw - pw) * w);
    float4 a1 = make_float4(px * w, py * w, pz * w, pw * w);
    *reinterpret_cast<float4*>(&agg[(size_t)node * 128 + c4]) = a0;
    *reinterpret_cast<float4*>(&agg[(size_t)node * 128 + 64 + c4]) = a1;
}

// ---------------------------------------------------------------------------
// Hidden GEMM v48 (R5 winner, verbatim): 64x64 tile, 128 threads, micro 4x8,
// LDS dbuf with register prefetch.
// ---------------------------------------------------------------------------
__global__ __launch_bounds__(128) void hidden_gemm_48(
    const float* __restrict__ agg, const float* __restrict__ in,
    const float* __restrict__ B, const float* __restrict__ bias,
    int n, int mode, float* __restrict__ u_out,
    const float* __restrict__ hbuf, const float* __restrict__ acc_in,
    float* __restrict__ acc_out, float* __restrict__ t_out,
    float c1, float c2, float c3) {
    __shared__ __align__(16) float As[2][16][68];
    __shared__ __align__(16) float Bs[2][16][68];
    const int t = threadIdx.x;            // 0..127
    const int row0 = blockIdx.x * 64;
    const int ty = t >> 3, tx = t & 7;    // 16x8 thread grid, micro 4x8
    const int arow = t >> 1, alk = (t & 1) << 3;   // A staging: 2 float4/thread
    const int bkk = t >> 3, bcl = (t & 7) << 3;    // B staging: 2 float4/thread

    float4 a0v = make_float4(0.f, 0.f, 0.f, 0.f);
    float4 a1v = make_float4(0.f, 0.f, 0.f, 0.f);
    {
        int r = row0 + arow;
        if (r < n) {
            a0v = *reinterpret_cast<const float4*>(&agg[(size_t)r * 128 + alk]);
            a1v = *reinterpret_cast<const float4*>(&agg[(size_t)r * 128 + alk + 4]);
        }
    }
    float4 b0v = *reinterpret_cast<const float4*>(&B[(size_t)bkk * 64 + bcl]);
    float4 b1v = *reinterpret_cast<const float4*>(&B[(size_t)bkk * 64 + bcl + 4]);
    As[0][alk + 0][arow] = a0v.x; As[0][alk + 1][arow] = a0v.y;
    As[0][alk + 2][arow] = a0v.z; As[0][alk + 3][arow] = a0v.w;
    As[0][alk + 4][arow] = a1v.x; As[0][alk + 5][arow] = a1v.y;
    As[0][alk + 6][arow] = a1v.z; As[0][alk + 7][arow] = a1v.w;
    *reinterpret_cast<float4*>(&Bs[0][bkk][bcl])     = b0v;
    *reinterpret_cast<float4*>(&Bs[0][bkk][bcl + 4]) = b1v;
    __syncthreads();

    float acc[4][8];
    #pragma unroll
    for (int i = 0; i < 4; ++i)
        #pragma unroll
        for (int j = 0; j < 8; ++j) acc[i][j] = 0.f;

    for (int kt = 0; kt < 12; ++kt) {
        const int cur = kt & 1;
        if (kt + 1 < 12) {
            int k0 = (kt + 1) << 4;
            int r = row0 + arow;
            int kk = k0 + alk;
            a0v = make_float4(0.f, 0.f, 0.f, 0.f);
            a1v = make_float4(0.f, 0.f, 0.f, 0.f);
            if (r < n) {
                if (kk < 128) {
                    a0v = *reinterpret_cast<const float4*>(&agg[(size_t)r * 128 + kk]);
                    a1v = *reinterpret_cast<const float4*>(&agg[(size_t)r * 128 + kk + 4]);
                } else {
                    a0v = *reinterpret_cast<const float4*>(&in[(size_t)r * 64 + (kk - 128)]);
                    a1v = *reinterpret_cast<const float4*>(&in[(size_t)r * 64 + (kk - 124)]);
                }
            }
            b0v = *reinterpret_cast<const float4*>(&B[(size_t)(k0 + bkk) * 64 + bcl]);
            b1v = *reinterpret_cast<const float4*>(&B[(size_t)(k0 + bkk) * 64 + bcl + 4]);
        }
        #pragma unroll
        for (int kk = 0; kk < 16; ++kk) {
            float4 a4 = *reinterpret_cast<const float4*>(&As[cur][kk][ty << 2]);
            float4 b40 = *reinterpret_cast<const float4*>(&Bs[cur][kk][tx << 3]);
            float4 b41 = *reinterpret_cast<const float4*>(&Bs[cur][kk][(tx << 3) + 4]);
            float aa[4] = {a4.x, a4.y, a4.z, a4.w};
            float bb[8] = {b40.x, b40.y, b40.z, b40.w, b41.x, b41.y, b41.z, b41.w};
            #pragma unroll
            for (int i = 0; i < 4; ++i)
                #pragma unroll
                for (int j = 0; j < 8; ++j)
                    acc[i][j] = fmaf(aa[i], bb[j], acc[i][j]);
        }
        if (kt + 1 < 12) {
            const int nx = cur ^ 1;
            As[nx][alk + 0][arow] = a0v.x; As[nx][alk + 1][arow] = a0v.y;
            As[nx][alk + 2][arow] = a0v.z; As[nx][alk + 3][arow] = a0v.w;
            As[nx][alk + 4][arow] = a1v.x; As[nx][alk + 5][arow] = a1v.y;
            As[nx][alk + 6][arow] = a1v.z; As[nx][alk + 7][arow] = a1v.w;
            *reinterpret_cast<float4*>(&Bs[nx][bkk][bcl])     = b0v;
            *reinterpret_cast<float4*>(&Bs[nx][bkk][bcl + 4]) = b1v;
        }
        __syncthreads();
    }

    float4 bia0 = *reinterpret_cast<const float4*>(&bias[tx << 3]);
    float4 bia1 = *reinterpret_cast<const float4*>(&bias[(tx << 3) + 4]);
    #pragma unroll
    for (int i = 0; i < 4; ++i) {
        int r = row0 + (ty << 2) + i;
        if (r >= n) continue;
        size_t idx = (size_t)r * 64 + (tx << 3);
        float4 v0 = make_float4(acc[i][0] + bia0.x, acc[i][1] + bia0.y,
                                acc[i][2] + bia0.z, acc[i][3] + bia0.w);
        float4 v1 = make_float4(acc[i][4] + bia1.x, acc[i][5] + bia1.y,
                                acc[i][6] + bia1.z, acc[i][7] + bia1.w);
        if (mode == 0) {
            *reinterpret_cast<float4*>(&u_out[idx])     = v0;
            *reinterpret_cast<float4*>(&u_out[idx + 4]) = v1;
        } else {
            float4 ai0 = make_float4(0.f, 0.f, 0.f, 0.f);
            float4 ai1 = make_float4(0.f, 0.f, 0.f, 0.f);
            if (acc_in) {
                ai0 = *reinterpret_cast<const float4*>(&acc_in[idx]);
                ai1 = *reinterpret_cast<const float4*>(&acc_in[idx + 4]);
            }
            float4 an0 = make_float4(ai0.x + c3 * v0.x, ai0.y + c3 * v0.y,
                                     ai0.z + c3 * v0.z, ai0.w + c3 * v0.w);
            float4 an1 = make_float4(ai1.x + c3 * v1.x, ai1.y + c3 * v1.y,
                                     ai1.z + c3 * v1.z, ai1.w + c3 * v1.w);
            *reinterpret_cast<float4*>(&acc_out[idx])     = an0;
            *reinterpret_cast<float4*>(&acc_out[idx + 4]) = an1;
            float4 hb0 = *reinterpret_cast<const float4*>(&hbuf[idx]);
            float4 hb1 = *reinterpret_cast<const float4*>(&hbuf[idx + 4]);
            float4 to0 = make_float4(hb0.x + c1 * v0.x + c2 * an0.x,
                                     hb0.y + c1 * v0.y + c2 * an0.y,
                                     hb0.z + c1 * v0.z + c2 * an0.z,
                                     hb0.w + c1 * v0.w + c2 * an0.w);
            float4 to1 = make_float4(hb1.x + c1 * v1.x + c2 * an1.x,
                                     hb1.y + c1 * v1.y + c2 * an1.y,
                                     hb1.z + c1 * v1.z + c2 * an1.z,
                                     hb1.w + c1 * v1.w + c2 * an1.w);
            *reinterpret_cast<float4*>(&t_out[idx])     = to0;
            *reinterpret_cast<float4*>(&t_out[idx + 4]) = to1;
        }
    }
}

// ---------------------------------------------------------------------------
// conv1 GEMM v6 (R7): v5's 32x192 tile / 4x12 micro, + register prefetch of
// the NEXT k-tile issued BEFORE computing the current one (issue-early /
// write-late, single LDS buffer; barrier count unchanged at 2/iter:
// compute -> barrier -> LDS-write -> barrier). v5 measured VALUBusy 42% vs
// its ~50% LDS-issue ceiling; the gap is global-load latency exposed between
// barriers. Register cost ~+28 VGPR on v5's 52 -> ~80, no spill (r1's 248-
// VGPR failure was acc=96 + dbuf; here acc=48, single buffer). k-order per
// output unchanged (kt asc, kk asc, one accumulator) -> bitwise identical.
// ---------------------------------------------------------------------------
__global__ __launch_bounds__(128) void conv1_gemm_v6(const float* __restrict__ x,
                                                     const float* __restrict__ B,
                                                     int n, float* __restrict__ yz,
                                                     float* __restrict__ base,
                                                     const float* __restrict__ b1) {
    __shared__ __align__(16) float As[16][36];
    __shared__ __align__(16) float Bs[16][200];
    const int t = threadIdx.x;
    const int row0 = blockIdx.x * 32;
    const int ty = t >> 4, tx = t & 15;
    const int arow = t >> 2, alk = (t & 3) << 2;
    const int bkk0 = t >> 4, bcol = (t & 15) << 2;

    // prologue: stage tile 0
    {
        float4 av = make_float4(0.f, 0.f, 0.f, 0.f);
        int r = row0 + arow;
        if (r < n)
            av = *reinterpret_cast<const float4*>(&x[(size_t)r * 256 + alk]);
        As[alk + 0][arow] = av.x; As[alk + 1][arow] = av.y;
        As[alk + 2][arow] = av.z; As[alk + 3][arow] = av.w;
        #pragma unroll
        for (int hh = 0; hh < 2; ++hh) {
            int kk = bkk0 + 8 * hh;
            const float* bp = &B[(size_t)kk * 192 + bcol];
            *reinterpret_cast<float4*>(&Bs[kk][bcol])       = *reinterpret_cast<const float4*>(bp);
            *reinterpret_cast<float4*>(&Bs[kk][bcol + 64])  = *reinterpret_cast<const float4*>(bp + 64);
            *reinterpret_cast<float4*>(&Bs[kk][bcol + 128]) = *reinterpret_cast<const float4*>(bp + 128);
        }
    }
    __syncthreads();

    float acc[4][12];
    #pragma unroll
    for (int i = 0; i < 4; ++i)
        #pragma unroll
        for (int j = 0; j < 12; ++j) acc[i][j] = 0.f;

    float4 apf;
    float4 bpf[2][3];
    for (int kt = 0; kt < 16; ++kt) {
        if (kt + 1 < 16) {
            int k0n = (kt + 1) << 4;
            apf = make_float4(0.f, 0.f, 0.f, 0.f);
            int r = row0 + arow;
            if (r < n)
                apf = *reinterpret_cast<const float4*>(&x[(size_t)r * 256 + k0n + alk]);
            #pragma unroll
            for (int hh = 0; hh < 2; ++hh) {
                int kk = bkk0 + 8 * hh;
                const float* bp = &B[(size_t)(k0n + kk) * 192 + bcol];
                bpf[hh][0] = *reinterpret_cast<const float4*>(bp);
                bpf[hh][1] = *reinterpret_cast<const float4*>(bp + 64);
                bpf[hh][2] = *reinterpret_cast<const float4*>(bp + 128);
            }
        }
        #pragma unroll
        for (int kk = 0; kk < 16; ++kk) {
            float4 a0 = *reinterpret_cast<const float4*>(&As[kk][ty << 2]);
            float4 b0 = *reinterpret_cast<const float4*>(&Bs[kk][tx << 2]);
            float4 b1q = *reinterpret_cast<const float4*>(&Bs[kk][(tx << 2) + 64]);
            float4 b2q = *reinterpret_cast<const float4*>(&Bs[kk][(tx << 2) + 128]);
            float aa[4] = {a0.x, a0.y, a0.z, a0.w};
            float bb[12] = {b0.x, b0.y, b0.z, b0.w, b1q.x, b1q.y, b1q.z, b1q.w,
                            b2q.x, b2q.y, b2q.z, b2q.w};
            #pragma unroll
            for (int i = 0; i < 4; ++i)
                #pragma unroll
                for (int j = 0; j < 12; ++j)
                    acc[i][j] = fmaf(aa[i], bb[j], acc[i][j]);
        }
        __syncthreads();
        if (kt + 1 < 16) {
            As[alk + 0][arow] = apf.x; As[alk + 1][arow] = apf.y;
            As[alk + 2][arow] = apf.z; As[alk + 3][arow] = apf.w;
            #pragma unroll
            for (int hh = 0; hh < 2; ++hh) {
                int kk = bkk0 + 8 * hh;
                *reinterpret_cast<float4*>(&Bs[kk][bcol])       = bpf[hh][0];
                *reinterpret_cast<float4*>(&Bs[kk][bcol + 64])  = bpf[hh][1];
                *reinterpret_cast<float4*>(&Bs[kk][bcol + 128]) = bpf[hh][2];
            }
        }
        __syncthreads();
    }

    float4 bb4 = *reinterpret_cast<const float4*>(&b1[tx << 2]);
    #pragma unroll
    for (int i = 0; i < 4; ++i) {
        int r = row0 + (ty << 2) + i;
        if (r >= n) continue;
        float4 q0 = make_float4(acc[i][0], acc[i][1], acc[i][2], acc[i][3]);
        float4 q1 = make_float4(acc[i][4], acc[i][5], acc[i][6], acc[i][7]);
        float4 q2 = make_float4(acc[i][8] + bb4.x, acc[i][9] + bb4.y,
                                acc[i][10] + bb4.z, acc[i][11] + bb4.w);
        *reinterpret_cast<float4*>(&yz[(size_t)r * 128 + (tx << 2)]) = q0;
        *reinterpret_cast<float4*>(&yz[(size_t)r * 128 + 64 + (tx << 2)]) = q1;
        *reinterpret_cast<float4*>(&base[(size_t)r * 64 + (tx << 2)]) = q2;
    }
}

// ---------------------------------------------------------------------------
// conv1 edge transform (8 lanes/node x 8 ch) — R5 form (line-coalesced:
// 8 lanes cover the full 64-ch y row and z row; 512B/edge fully used).
// ---------------------------------------------------------------------------
__global__ __launch_bounds__(256) void edge_tf64_v8(const float* __restrict__ yz,
                                                    const int* __restrict__ rowp,
                                                    const int2* __restrict__ epk,
                                                    const float* __restrict__ invd,
                                                    const float* __restrict__ base,
                                                    float* __restrict__ out, int n) {
    int gid = blockIdx.x * 256 + threadIdx.x;
    int node = gid >> 3;
    if (node >= n) return;
    int c8 = (gid & 7) << 3;
    int e = rowp[node], eend = rowp[node + 1];
    float a[8] = {0.f, 0.f, 0.f, 0.f, 0.f, 0.f, 0.f, 0.f};
    for (; e + 2 <= eend; e += 2) {
        int2 q0 = epk[e], q1 = epk[e + 1];
        int s0 = q0.x, s1 = q1.x;
        float p0 = __int_as_float(q0.y), p1 = __int_as_float(q1.y);
        float4 y0a = *reinterpret_cast<const float4*>(&yz[(size_t)s0 * 128 + c8]);
        float4 y0b = *reinterpret_cast<const float4*>(&yz[(size_t)s0 * 128 + c8 + 4]);
        float4 z0a = *reinterpret_cast<const float4*>(&yz[(size_t)s0 * 128 + 64 + c8]);
        float4 z0b = *reinterpret_cast<const float4*>(&yz[(size_t)s0 * 128 + 64 + c8 + 4]);
        float4 y1a = *reinterpret_cast<const float4*>(&yz[(size_t)s1 * 128 + c8]);
        float4 y1b = *reinterpret_cast<const float4*>(&yz[(size_t)s1 * 128 + c8 + 4]);
        float4 z1a = *reinterpret_cast<const float4*>(&yz[(size_t)s1 * 128 + 64 + c8]);
        float4 z1b = *reinterpret_cast<const float4*>(&yz[(size_t)s1 * 128 + 64 + c8 + 4]);
        const float* ya0 = &y0a.x; const float* yb0 = &y0b.x;
        const float* za0 = &z0a.x; const float* zb0 = &z0b.x;
        const float* ya1 = &y1a.x; const float* yb1 = &y1b.x;
        const float* za1 = &z1a.x; const float* zb1 = &z1b.x;
        #pragma unroll
        for (int j = 0; j < 4; ++j) {
            a[j]     += fmaf(p0, za0[j] - ya0[j], ya0[j]) + fmaf(p1, za1[j] - ya1[j], ya1[j]);
            a[4 + j] += fmaf(p0, zb0[j] - yb0[j], yb0[j]) + fmaf(p1, zb1[j] - yb1[j], yb1[j]);
        }
    }
    for (; e < eend; ++e) {
        int2 q = epk[e];
        int s = q.x;
        float pe = __int_as_float(q.y);
        float4 ya = *reinterpret_cast<const float4*>(&yz[(size_t)s * 128 + c8]);
        float4 yb = *reinterpret_cast<const float4*>(&yz[(size_t)s * 128 + c8 + 4]);
        float4 za = *reinterpret_cast<const float4*>(&yz[(size_t)s * 128 + 64 + c8]);
        float4 zb = *reinterpret_cast<const float4*>(&yz[(size_t)s * 128 + 64 + c8 + 4]);
        const float* fy = &ya.x; const float* gy = &yb.x;
        const float* fz = &za.x; const float* gz = &zb.x;
        #pragma unroll
        for (int j = 0; j < 4; ++j) {
            a[j]     += fmaf(pe, fz[j] - fy[j], fy[j]);
            a[4 + j] += fmaf(pe, gz[j] - gy[j], gy[j]);
        }
    }
    float w = invd[node];
    size_t idx = (size_t)node * 64 + c8;
    float4 ba = *reinterpret_cast<const float4*>(&base[idx]);
    float4 bbv = *reinterpret_cast<const float4*>(&base[idx + 4]);
    float4 o0 = make_float4(tanhf(fmaf(a[0], w, ba.x)), tanhf(fmaf(a[1], w, ba.y)),
                            tanhf(fmaf(a[2], w, ba.z)), tanhf(fmaf(a[3], w, ba.w)));
    float4 o1 = make_float4(tanhf(fmaf(a[4], w, bbv.x)), tanhf(fmaf(a[5], w, bbv.y)),
                            tanhf(fmaf(a[6], w, bbv.z)), tanhf(fmaf(a[7], w, bbv.w)));
    *reinterpret_cast<float4*>(&out[idx]) = o0;
    *reinterpret_cast<float4*>(&out[idx + 4]) = o1;
}

__global__ __launch_bounds__(256) void edge_tf16_lsm(const float* __restrict__ yz,
                                                     const int* __restrict__ rowp,
                                                     const int2* __restrict__ epk,
                                                     const float* __restrict__ invd,
                                                     const float* __restrict__ base,
                                                     float* __restrict__ out, int n) {
    int gid = blockIdx.x * 256 + threadIdx.x;
    int node = gid >> 4;
    if (node >= n) return;
    int c = gid & 15;
    int e = rowp[node], eend = rowp[node + 1];
    float a = 0.f;
    for (; e + 4 <= eend; e += 4) {
        int2 q0 = epk[e], q1 = epk[e + 1], q2 = epk[e + 2], q3 = epk[e + 3];
        int s0 = q0.x, s1 = q1.x, s2 = q2.x, s3 = q3.x;
        float p0 = __int_as_float(q0.y), p1 = __int_as_float(q1.y);
        float p2 = __int_as_float(q2.y), p3 = __int_as_float(q3.y);
        float y0 = yz[(size_t)s0 * 32 + c],      z0 = yz[(size_t)s0 * 32 + 16 + c];
        float y1 = yz[(size_t)s1 * 32 + c],      z1 = yz[(size_t)s1 * 32 + 16 + c];
        float y2 = yz[(size_t)s2 * 32 + c],      z2 = yz[(size_t)s2 * 32 + 16 + c];
        float y3 = yz[(size_t)s3 * 32 + c],      z3 = yz[(size_t)s3 * 32 + 16 + c];
        a += fmaf(p0, z0 - y0, y0);
        a += fmaf(p1, z1 - y1, y1);
        a += fmaf(p2, z2 - y2, y2);
        a += fmaf(p3, z3 - y3, y3);
    }
    for (; e < eend; ++e) {
        int2 q = epk[e];
        int s = q.x; float pe = __int_as_float(q.y);
        float y = yz[(size_t)s * 32 + c], z = yz[(size_t)s * 32 + 16 + c];
        a += fmaf(pe, z - y, y);
    }
    float o = tanhf(a * invd[node] + base[(size_t)node * 16 + c]);
    float m = o;
    #pragma unroll
    for (int off = 8; off >= 1; off >>= 1) m = fmaxf(m, __shfl_xor(m, off, 16));
    float ex = expf(o - m);
    float s = ex;
    #pragma unroll
    for (int off = 8; off >= 1; off >>= 1) s += __shfl_xor(s, off, 16);
    out[(size_t)node * 16 + c] = (o - m) - logf(s);
}

// ---------------------------------------------------------------------------
// conv2 GEMM (K=64, M=48)
// ---------------------------------------------------------------------------
__global__ __launch_bounds__(256) void gemm_tiled(
    const float* __restrict__ A0, int lda0, int K0,
    const float* __restrict__ A1, int lda1,
    const float* __restrict__ B,
    int n, int K, int M,
    float* __restrict__ out0, int w0, const float* __restrict__ bias0,
    float* __restrict__ out1, int w1, const float* __restrict__ bias1,
    int split) {
    __shared__ __align__(16) float As[16][68];
    __shared__ __align__(16) float Bs[16][68];
    const int t = threadIdx.x;
    const int row0 = blockIdx.x * 64;
    const int col0 = blockIdx.y * 64;
    const int ty = t >> 4, tx = t & 15;
    const int lrow = t >> 2, lk = (t & 3) << 2;
    const int bkk = t >> 4, bcol = (t & 15) << 2;
    float acc[4][4];
    #pragma unroll
    for (int i = 0; i < 4; ++i)
        #pragma unroll
        for (int j = 0; j < 4; ++j) acc[i][j] = 0.f;

    for (int k0 = 0; k0 < K; k0 += 16) {
        float4 av = make_float4(0.f, 0.f, 0.f, 0.f);
        {
            int r = row0 + lrow;
            if (r < n) {
                int kk = k0 + lk;
                const float* src = (kk < K0)
                    ? (A0 + (size_t)r * lda0 + kk)
                    : (A1 + (size_t)r * lda1 + (kk - K0));
                av = *reinterpret_cast<const float4*>(src);
            }
        }
        float4 bv = make_float4(0.f, 0.f, 0.f, 0.f);
        {
            int c = col0 + bcol;
            int kk = k0 + bkk;
            if (c < M) bv = *reinterpret_cast<const float4*>(B + (size_t)kk * M + c);
        }
        As[lk + 0][lrow] = av.x; As[lk + 1][lrow] = av.y;
        As[lk + 2][lrow] = av.z; As[lk + 3][lrow] = av.w;
        *reinterpret_cast<float4*>(&Bs[bkk][bcol]) = bv;
        __syncthreads();
        #pragma unroll
        for (int kk = 0; kk < 16; ++kk) {
            float4 a4 = *reinterpret_cast<const float4*>(&As[kk][ty << 2]);
            float4 b4 = *reinterpret_cast<const float4*>(&Bs[kk][tx << 2]);
            float aa[4] = {a4.x, a4.y, a4.z, a4.w};
            float bb[4] = {b4.x, b4.y, b4.z, b4.w};
            #pragma unroll
            for (int i = 0; i < 4; ++i)
                #pragma unroll
                for (int j = 0; j < 4; ++j)
                    acc[i][j] = fmaf(aa[i], bb[j], acc[i][j]);
        }
        __syncthreads();
    }

    #pragma unroll
    for (int i = 0; i < 4; ++i) {
        int r = row0 + (ty << 2) + i;
        if (r >= n) continue;
        #pragma unroll
        for (int j = 0; j < 4; ++j) {
            int c = col0 + (tx << 2) + j;
            if (c >= M) continue;
            float v = acc[i][j];
            if (c < split) {
                if (bias0) v += bias0[c];
                out0[(size_t)r * w0 + c] = v;
            } else {
                int cc = c - split;
                if (bias1) v += bias1[cc];
                out1[(size_t)r * w1 + cc] = v;
            }
        }
    }
}

// ---------------------------------------------------------------------------
// Host-side launcher
// ---------------------------------------------------------------------------

static void hidden_conv(hipStream_t stream, const float* in, float* agg,
                        const int* rowp, const int2* epk,
                        const float* invd, const float* Bc, const float* bias, int n,
                        int mode, float* u_out,
                        const float* h, const float* acc_in, float* acc_out,
                        float* t_out, float c1, float c2, float c3) {
    edge_agg64_v5<<<ceil_div(n * 16, 256), 256, 0, stream>>>(in, rowp, epk, invd,
                                                             agg, n);
    hidden_gemm_48<<<ceil_div(n, 64), 128, 0, stream>>>(agg, in, Bc, bias, n, mode,
                                                        u_out, h, acc_in, acc_out,
                                                        t_out, c1, c2, c3);
}

extern "C" void kernel_launch(void* const* d_in, const int* in_sizes, int n_in,
                              void* d_out, int out_size, void* d_ws, size_t ws_size,
                              hipStream_t stream) {
    const float* x  = (const float*)d_in[0];
    const float* pE = (const float*)d_in[1];
    const int*   sr = (const int*)d_in[2];
    const int*   ds = (const int*)d_in[3];
    const float* W1 = (const float*)d_in[4];
    const float* R1 = (const float*)d_in[5];
    const float* b1 = (const float*)d_in[6];
    const float* Wa = (const float*)d_in[7];
    const float* Ra = (const float*)d_in[8];
    const float* ba = (const float*)d_in[9];
    const float* Wb = (const float*)d_in[10];
    const float* Rb = (const float*)d_in[11];
    const float* bb = (const float*)d_in[12];
    const float* W2 = (const float*)d_in[13];
    const float* R2 = (const float*)d_in[14];
    const float* b2 = (const float*)d_in[15];
    const int n = in_sizes[0] / 256;
    const int E = in_sizes[2];
    float* out = (float*)d_out;

    char* w = (char*)d_ws;
    auto alloc = [&](size_t bytes) -> void* {
        void* ptr = (void*)w;
        w += (bytes + 255) & ~(size_t)255;
        return ptr;
    };
    int nscan = ceil_div(n, 2048);
    int*   deg  = (int*)alloc((size_t)n * 4);
    int*   fill = (int*)alloc((size_t)n * 4);
    int*   rowp = (int*)alloc((size_t)(n + 1) * 4);
    float* invd = (float*)alloc((size_t)n * 4);
    int*   bsum = (int*)alloc((size_t)256 * 4);
    int*   ei   = (int*)alloc((size_t)E * 4);
    int2*  epk  = (int2*)alloc((size_t)E * 8);
    float* Bc1  = (float*)alloc((size_t)256 * 192 * 4);
    float* Bca  = (float*)alloc((size_t)192 * 64 * 4);
    float* Bcb  = (float*)alloc((size_t)192 * 64 * 4);
    float* Bc2  = (float*)alloc((size_t)64 * 48 * 4);
    float* big0 = (float*)alloc((size_t)n * 128 * 4);  // yz / agg buffer
    float* big1 = (float*)alloc((size_t)n * 64 * 4);   // base buffer
    float* h    = (float*)alloc((size_t)n * 64 * 4);
    float* u    = (float*)alloc((size_t)n * 64 * 4);
    float* tb   = (float*)alloc((size_t)n * 64 * 4);
    float* acc  = (float*)alloc((size_t)n * 64 * 4);

    const int PACK_TOTAL = 256 * 192 + 2 * 192 * 64 + 64 * 48;

    zero2<<<ceil_div(n, 256), 256, 0, stream>>>(deg, fill, n);
    pack_all<<<ceil_div(PACK_TOTAL, 256), 256, 0, stream>>>(W1, R1, Wa, Ra, Wb, Rb,
                                                            W2, R2, Bc1, Bca, Bcb, Bc2);
    hist_kernel<<<ceil_div(E, 256), 256, 0, stream>>>(ds, deg, E);
    scan_blocksum<<<nscan, 256, 0, stream>>>(deg, bsum, n);
    scan_tops<<<1, 256, 0, stream>>>(bsum, nscan);
    scan_final<<<nscan, 256, 0, stream>>>(deg, bsum, rowp, invd, n, E);
    scatter_idx<<<ceil_div(E, 256), 256, 0, stream>>>(ds, rowp, fill, ei, E);
    sort_fill<<<ceil_div(n, 256), 256, 0, stream>>>(rowp, ei, sr, pE, epk, n);

    // conv1: x @ [W1_0|W1_1|R1] -> yz(big0), base(big1)+b1; then edge transform
    conv1_gemm_v6<<<ceil_div(n, 32), 128, 0, stream>>>(x, Bc1, n, big0, big1, b1);
    edge_tf64_v8<<<ceil_div(n * 8, 256), 256, 0, stream>>>(big0, rowp, epk, invd,
                                                           big1, h, n);

    // RK4 over f(y) = conv_b(conv_a(y)), T=3
    // k1
    hidden_conv(stream, h, big0, rowp, epk, invd, Bca, ba, n, 0, u,
                nullptr, nullptr, nullptr, nullptr, 0.f, 0.f, 0.f);
    hidden_conv(stream, u, big0, rowp, epk, invd, Bcb, bb, n, 1, nullptr,
                h, nullptr, acc, tb, 1.5f, 0.f, 1.f);
    // k2
    hidden_conv(stream, tb, big0, rowp, epk, invd, Bca, ba, n, 0, u,
                nullptr, nullptr, nullptr, nullptr, 0.f, 0.f, 0.f);
    hidden_conv(stream, u, big0, rowp, epk, invd, Bcb, bb, n, 1, nullptr,
                h, acc, acc, tb, 1.5f, 0.f, 2.f);
    // k3
    hidden_conv(stream, tb, big0, rowp, epk, invd, Bca, ba, n, 0, u,
                nullptr, nullptr, nullptr, nullptr, 0.f, 0.f, 0.f);
    hidden_conv(stream, u, big0, rowp, epk, invd, Bcb, bb, n, 1, nullptr,
                h, acc, acc, tb, 3.f, 0.f, 2.f);
    // k4: t_out becomes h_new = h + 0.5*(k1+2k2+2k3+k4)
    hidden_conv(stream, tb, big0, rowp, epk, invd, Bca, ba, n, 0, u,
                nullptr, nullptr, nullptr, nullptr, 0.f, 0.f, 0.f);
    hidden_conv(stream, u, big0, rowp, epk, invd, Bcb, bb, n, 1, nullptr,
                h, acc, acc, tb, 0.f, 0.5f, 1.f);

    // conv2: h_new @ [W2_0|W2_1|R2] -> yz2(big0,w=32), base2(big1,w=16)+b2
    gemm_tiled<<<dim3(ceil_div(n, 64), 1), 256, 0, stream>>>(
        tb, 64, 64, nullptr, 0, Bc2, n, 64, 48,
        big0, 32, nullptr, big1, 16, b2, 32);
    edge_tf16_lsm<<<ceil_div(n * 16, 256), 256, 0, stream>>>(big0, rowp, epk, invd,
                                                             big1, out, n);
}

// Round 8
// 853.107 us; speedup vs baseline: 1.3846x; 1.1151x over previous
//
#include <hip/hip_runtime.h>
#include <math.h>

static inline int ceil_div(int a, int b) { return (a + b - 1) / b; }

// ---------------------------------------------------------------------------
// Setup kernels
// ---------------------------------------------------------------------------

__global__ __launch_bounds__(256) void zero2(int* __restrict__ a, int* __restrict__ b,
                                             int n) {
    int i = blockIdx.x * 256 + threadIdx.x;
    if (i < n) { a[i] = 0; b[i] = 0; }
}

__global__ __launch_bounds__(256) void hist_kernel(const int* __restrict__ dst,
                                                   int* __restrict__ deg, int E) {
    int e = blockIdx.x * 256 + threadIdx.x;
    if (e < E) atomicAdd(&deg[dst[e]], 1);
}

__global__ __launch_bounds__(256) void scan_blocksum(const int* __restrict__ deg,
                                                     int* __restrict__ bsum, int n) {
    __shared__ int red[256];
    int t = threadIdx.x;
    int base = blockIdx.x * 2048 + t * 8;
    int s = 0;
    #pragma unroll
    for (int i = 0; i < 8; ++i) {
        int idx = base + i;
        if (idx < n) s += deg[idx];
    }
    red[t] = s;
    __syncthreads();
    #pragma unroll
    for (int off = 128; off >= 1; off >>= 1) {
        if (t < off) red[t] += red[t + off];
        __syncthreads();
    }
    if (t == 0) bsum[blockIdx.x] = red[0];
}

__global__ __launch_bounds__(256) void scan_tops(int* __restrict__ bsum, int nb) {
    __shared__ int sh[256];
    int t = threadIdx.x;
    int orig = (t < nb) ? bsum[t] : 0;
    sh[t] = orig;
    __syncthreads();
    for (int off = 1; off < 256; off <<= 1) {
        int add = (t >= off) ? sh[t - off] : 0;
        __syncthreads();
        sh[t] += add;
        __syncthreads();
    }
    if (t < nb) bsum[t] = sh[t] - orig;  // exclusive prefix
}

__global__ __launch_bounds__(256) void scan_final(const int* __restrict__ deg,
                                                  const int* __restrict__ bsum,
                                                  int* __restrict__ rowp,
                                                  float* __restrict__ invd,
                                                  int n, int E) {
    __shared__ int sh[256];
    int t = threadIdx.x;
    int base = blockIdx.x * 2048 + t * 8;
    int loc[8];
    int s = 0;
    #pragma unroll
    for (int i = 0; i < 8; ++i) {
        int idx = base + i;
        int d = (idx < n) ? deg[idx] : 0;
        loc[i] = d;
        s += d;
    }
    sh[t] = s;
    __syncthreads();
    for (int off = 1; off < 256; off <<= 1) {
        int add = (t >= off) ? sh[t - off] : 0;
        __syncthreads();
        sh[t] += add;
        __syncthreads();
    }
    int run = bsum[blockIdx.x] + (sh[t] - s);
    #pragma unroll
    for (int i = 0; i < 8; ++i) {
        int idx = base + i;
        if (idx < n) {
            rowp[idx] = run;
            int d = loc[i];
            run += d;
            invd[idx] = 1.0f / (float)(d > 1 ? d : 1);
        }
    }
    if (blockIdx.x == 0 && t == 0) rowp[n] = E;
}

__global__ __launch_bounds__(256) void scatter_idx(const int* __restrict__ dst,
                                                   const int* __restrict__ rowp,
                                                   int* __restrict__ fill,
                                                   int* __restrict__ ei, int E) {
    int e = blockIdx.x * 256 + threadIdx.x;
    if (e >= E) return;
    int d = dst[e];
    int pos = rowp[d] + atomicAdd(&fill[d], 1);
    ei[pos] = e;
}

// Deterministic intra-node edge order (matches segment_sum's edge-index order).
// RK4 @ T=3 amplifies fp32 sum-order noise to O(1): determinism & order =
// correctness. NEVER change accumulation grouping downstream.
// Writes packed (src, p) pairs -> edge kernels do 1 VMEM instead of 2 for
// edge metadata. Values and order unchanged.
__global__ __launch_bounds__(256) void sort_fill(const int* __restrict__ rowp,
                                                 int* __restrict__ ei,
                                                 const int* __restrict__ src,
                                                 const float* __restrict__ p,
                                                 int2* __restrict__ epk, int n) {
    int node = blockIdx.x * 256 + threadIdx.x;
    if (node >= n) return;
    int b = rowp[node], e = rowp[node + 1];
    for (int i = b + 1; i < e; ++i) {
        int key = ei[i];
        int j = i - 1;
        while (j >= b && ei[j] > key) { ei[j + 1] = ei[j]; --j; }
        ei[j + 1] = key;
    }
    for (int i = b; i < e; ++i) {
        int id = ei[i];
        epk[i] = make_int2(src[id], __float_as_int(p[id]));
    }
}

__global__ __launch_bounds__(256) void pack_all(
    const float* __restrict__ W1, const float* __restrict__ R1,
    const float* __restrict__ Wa, const float* __restrict__ Ra,
    const float* __restrict__ Wb, const float* __restrict__ Rb,
    const float* __restrict__ W2, const float* __restrict__ R2,
    float* __restrict__ Bc1, float* __restrict__ Bca,
    float* __restrict__ Bcb, float* __restrict__ Bc2) {
    int idx = blockIdx.x * 256 + threadIdx.x;
    const int S1 = 256 * 192, S2 = 192 * 64, S4 = 64 * 48;
    if (idx < S1) {
        int k = idx / 192, c = idx % 192;
        float v;
        if (c < 64)       v = W1[k * 64 + c];
        else if (c < 128) v = W1[256 * 64 + k * 64 + (c - 64)];
        else              v = R1[k * 64 + (c - 128)];
        Bc1[idx] = v;
        return;
    }
    idx -= S1;
    if (idx < S2) { Bca[idx] = (idx < 8192) ? Wa[idx] : Ra[idx - 8192]; return; }
    idx -= S2;
    if (idx < S2) { Bcb[idx] = (idx < 8192) ? Wb[idx] : Rb[idx - 8192]; return; }
    idx -= S2;
    if (idx < S4) {
        int k = idx / 48, c = idx % 48;
        float v;
        if (c < 16)      v = W2[k * 16 + c];
        else if (c < 32) v = W2[64 * 16 + k * 16 + (c - 16)];
        else             v = R2[k * 16 + (c - 32)];
        Bc2[idx] = v;
    }
}

// ---------------------------------------------------------------------------
// Edge aggregation (hidden convs): 16 lanes/node x float4 — R5 form.
// Memory-service-bound at the chip's random line-granular gather rate
// (R4: load-balancing neutral; R6: channel-slicing multiplies line traffic).
// 16 lanes cover a node's full 64-ch row (256B, fully used). Do not slice.
// ---------------------------------------------------------------------------
__global__ __launch_bounds__(256) void edge_agg64_v5(const float* __restrict__ x,
                                                     const int* __restrict__ rowp,
                                                     const int2* __restrict__ epk,
                                                     const float* __restrict__ invd,
                                                     float* __restrict__ agg, int n) {
    int gid = blockIdx.x * 256 + threadIdx.x;
    int node = gid >> 4;
    if (node >= n) return;
    int c4 = (gid & 15) << 2;
    int e = rowp[node], eend = rowp[node + 1];
    float sx = 0.f, sy = 0.f, sz = 0.f, sw = 0.f;
    float px = 0.f, py = 0.f, pz = 0.f, pw = 0.f;
    for (; e + 4 <= eend; e += 4) {
        int2 q0 = epk[e], q1 = epk[e + 1], q2 = epk[e + 2], q3 = epk[e + 3];
        int s0 = q0.x, s1 = q1.x, s2 = q2.x, s3 = q3.x;
        float p0 = __int_as_float(q0.y), p1 = __int_as_float(q1.y);
        float p2 = __int_as_float(q2.y), p3 = __int_as_float(q3.y);
        float4 v0 = *reinterpret_cast<const float4*>(&x[(size_t)s0 * 64 + c4]);
        float4 v1 = *reinterpret_cast<const float4*>(&x[(size_t)s1 * 64 + c4]);
        float4 v2 = *reinterpret_cast<const float4*>(&x[(size_t)s2 * 64 + c4]);
        float4 v3 = *reinterpret_cast<const float4*>(&x[(size_t)s3 * 64 + c4]);
        sx += (v0.x + v1.x) + (v2.x + v3.x);
        sy += (v0.y + v1.y) + (v2.y + v3.y);
        sz += (v0.z + v1.z) + (v2.z + v3.z);
        sw += (v0.w + v1.w) + (v2.w + v3.w);
        px = fmaf(p0, v0.x, fmaf(p1, v1.x, fmaf(p2, v2.x, fmaf(p3, v3.x, px))));
        py = fmaf(p0, v0.y, fmaf(p1, v1.y, fmaf(p2, v2.y, fmaf(p3, v3.y, py))));
        pz = fmaf(p0, v0.z, fmaf(p1, v1.z, fmaf(p2, v2.z, fmaf(p3, v3.z, pz))));
        pw = fmaf(p0, v0.w, fmaf(p1, v1.w, fmaf(p2, v2.w, fmaf(p3, v3.w, pw))));
    }
    for (; e < eend; ++e) {
        int2 q = epk[e];
        int s = q.x;
        float pe = __int_as_float(q.y);
        float4 v = *reinterpret_cast<const float4*>(&x[(size_t)s * 64 + c4]);
        sx += v.x; sy += v.y; sz += v.z; sw += v.w;
        px = fmaf(pe, v.x, px); py = fmaf(pe, v.y, py);
        pz = fmaf(pe, v.z, pz); pw = fmaf(pe, v.w, pw);
    }
    float w = invd[node];
    float4 a0 = make_float4((sx - px) * w, (sy - py) * w, (sz - pz) * w, (sw - pw) * w);
    float4 a1 = make_float4(px * w, py * w, pz * w, pw * w);
    *reinterpret_cast<float4*>(&agg[(size_t)node * 128 + c4]) = a0;
    *reinterpret_cast<float4*>(&agg[(size_t)node * 128 + 64 + c4]) = a1;
}

// ---------------------------------------------------------------------------
// Hidden GEMM v48 (R5 winner, verbatim): 64x64 tile, 128 threads, micro 4x8,
// LDS dbuf with register prefetch. 0.094 ds_read_b128/FMA — validated win
// over the 4x4/256t variant (R5 A/B). Do not add more prefetch state: v4/v6
// both spilled (VGPR 248/164).
// ---------------------------------------------------------------------------
__global__ __launch_bounds__(128) void hidden_gemm_48(
    const float* __restrict__ agg, const float* __restrict__ in,
    const float* __restrict__ B, const float* __restrict__ bias,
    int n, int mode, float* __restrict__ u_out,
    const float* __restrict__ hbuf, const float* __restrict__ acc_in,
    float* __restrict__ acc_out, float* __restrict__ t_out,
    float c1, float c2, float c3) {
    __shared__ __align__(16) float As[2][16][68];
    __shared__ __align__(16) float Bs[2][16][68];
    const int t = threadIdx.x;            // 0..127
    const int row0 = blockIdx.x * 64;
    const int ty = t >> 3, tx = t & 7;    // 16x8 thread grid, micro 4x8
    const int arow = t >> 1, alk = (t & 1) << 3;   // A staging: 2 float4/thread
    const int bkk = t >> 3, bcl = (t & 7) << 3;    // B staging: 2 float4/thread

    float4 a0v = make_float4(0.f, 0.f, 0.f, 0.f);
    float4 a1v = make_float4(0.f, 0.f, 0.f, 0.f);
    {
        int r = row0 + arow;
        if (r < n) {
            a0v = *reinterpret_cast<const float4*>(&agg[(size_t)r * 128 + alk]);
            a1v = *reinterpret_cast<const float4*>(&agg[(size_t)r * 128 + alk + 4]);
        }
    }
    float4 b0v = *reinterpret_cast<const float4*>(&B[(size_t)bkk * 64 + bcl]);
    float4 b1v = *reinterpret_cast<const float4*>(&B[(size_t)bkk * 64 + bcl + 4]);
    As[0][alk + 0][arow] = a0v.x; As[0][alk + 1][arow] = a0v.y;
    As[0][alk + 2][arow] = a0v.z; As[0][alk + 3][arow] = a0v.w;
    As[0][alk + 4][arow] = a1v.x; As[0][alk + 5][arow] = a1v.y;
    As[0][alk + 6][arow] = a1v.z; As[0][alk + 7][arow] = a1v.w;
    *reinterpret_cast<float4*>(&Bs[0][bkk][bcl])     = b0v;
    *reinterpret_cast<float4*>(&Bs[0][bkk][bcl + 4]) = b1v;
    __syncthreads();

    float acc[4][8];
    #pragma unroll
    for (int i = 0; i < 4; ++i)
        #pragma unroll
        for (int j = 0; j < 8; ++j) acc[i][j] = 0.f;

    for (int kt = 0; kt < 12; ++kt) {
        const int cur = kt & 1;
        if (kt + 1 < 12) {
            int k0 = (kt + 1) << 4;
            int r = row0 + arow;
            int kk = k0 + alk;
            a0v = make_float4(0.f, 0.f, 0.f, 0.f);
            a1v = make_float4(0.f, 0.f, 0.f, 0.f);
            if (r < n) {
                if (kk < 128) {
                    a0v = *reinterpret_cast<const float4*>(&agg[(size_t)r * 128 + kk]);
                    a1v = *reinterpret_cast<const float4*>(&agg[(size_t)r * 128 + kk + 4]);
                } else {
                    a0v = *reinterpret_cast<const float4*>(&in[(size_t)r * 64 + (kk - 128)]);
                    a1v = *reinterpret_cast<const float4*>(&in[(size_t)r * 64 + (kk - 124)]);
                }
            }
            b0v = *reinterpret_cast<const float4*>(&B[(size_t)(k0 + bkk) * 64 + bcl]);
            b1v = *reinterpret_cast<const float4*>(&B[(size_t)(k0 + bkk) * 64 + bcl + 4]);
        }
        #pragma unroll
        for (int kk = 0; kk < 16; ++kk) {
            float4 a4 = *reinterpret_cast<const float4*>(&As[cur][kk][ty << 2]);
            float4 b40 = *reinterpret_cast<const float4*>(&Bs[cur][kk][tx << 3]);
            float4 b41 = *reinterpret_cast<const float4*>(&Bs[cur][kk][(tx << 3) + 4]);
            float aa[4] = {a4.x, a4.y, a4.z, a4.w};
            float bb[8] = {b40.x, b40.y, b40.z, b40.w, b41.x, b41.y, b41.z, b41.w};
            #pragma unroll
            for (int i = 0; i < 4; ++i)
                #pragma unroll
                for (int j = 0; j < 8; ++j)
                    acc[i][j] = fmaf(aa[i], bb[j], acc[i][j]);
        }
        if (kt + 1 < 12) {
            const int nx = cur ^ 1;
            As[nx][alk + 0][arow] = a0v.x; As[nx][alk + 1][arow] = a0v.y;
            As[nx][alk + 2][arow] = a0v.z; As[nx][alk + 3][arow] = a0v.w;
            As[nx][alk + 4][arow] = a1v.x; As[nx][alk + 5][arow] = a1v.y;
            As[nx][alk + 6][arow] = a1v.z; As[nx][alk + 7][arow] = a1v.w;
            *reinterpret_cast<float4*>(&Bs[nx][bkk][bcl])     = b0v;
            *reinterpret_cast<float4*>(&Bs[nx][bkk][bcl + 4]) = b1v;
        }
        __syncthreads();
    }

    float4 bia0 = *reinterpret_cast<const float4*>(&bias[tx << 3]);
    float4 bia1 = *reinterpret_cast<const float4*>(&bias[(tx << 3) + 4]);
    #pragma unroll
    for (int i = 0; i < 4; ++i) {
        int r = row0 + (ty << 2) + i;
        if (r >= n) continue;
        size_t idx = (size_t)r * 64 + (tx << 3);
        float4 v0 = make_float4(acc[i][0] + bia0.x, acc[i][1] + bia0.y,
                                acc[i][2] + bia0.z, acc[i][3] + bia0.w);
        float4 v1 = make_float4(acc[i][4] + bia1.x, acc[i][5] + bia1.y,
                                acc[i][6] + bia1.z, acc[i][7] + bia1.w);
        if (mode == 0) {
            *reinterpret_cast<float4*>(&u_out[idx])     = v0;
            *reinterpret_cast<float4*>(&u_out[idx + 4]) = v1;
        } else {
            float4 ai0 = make_float4(0.f, 0.f, 0.f, 0.f);
            float4 ai1 = make_float4(0.f, 0.f, 0.f, 0.f);
            if (acc_in) {
                ai0 = *reinterpret_cast<const float4*>(&acc_in[idx]);
                ai1 = *reinterpret_cast<const float4*>(&acc_in[idx + 4]);
            }
            float4 an0 = make_float4(ai0.x + c3 * v0.x, ai0.y + c3 * v0.y,
                                     ai0.z + c3 * v0.z, ai0.w + c3 * v0.w);
            float4 an1 = make_float4(ai1.x + c3 * v1.x, ai1.y + c3 * v1.y,
                                     ai1.z + c3 * v1.z, ai1.w + c3 * v1.w);
            *reinterpret_cast<float4*>(&acc_out[idx])     = an0;
            *reinterpret_cast<float4*>(&acc_out[idx + 4]) = an1;
            float4 hb0 = *reinterpret_cast<const float4*>(&hbuf[idx]);
            float4 hb1 = *reinterpret_cast<const float4*>(&hbuf[idx + 4]);
            float4 to0 = make_float4(hb0.x + c1 * v0.x + c2 * an0.x,
                                     hb0.y + c1 * v0.y + c2 * an0.y,
                                     hb0.z + c1 * v0.z + c2 * an0.z,
                                     hb0.w + c1 * v0.w + c2 * an0.w);
            float4 to1 = make_float4(hb1.x + c1 * v1.x + c2 * an1.x,
                                     hb1.y + c1 * v1.y + c2 * an1.y,
                                     hb1.z + c1 * v1.z + c2 * an1.z,
                                     hb1.w + c1 * v1.w + c2 * an1.w);
            *reinterpret_cast<float4*>(&t_out[idx])     = to0;
            *reinterpret_cast<float4*>(&t_out[idx + 4]) = to1;
        }
    }
}

// ---------------------------------------------------------------------------
// conv1 GEMM v5 (FINAL): 32-row x 192-col tile, 128 threads, micro 4x12.
// 84us at VALUBusy 42% vs ~50% LDS-issue structural ceiling (~85% of bound).
// v4 (LDS dbuf, VGPR 248) and v6 (register prefetch, VGPR 164) both spilled
// and regressed 2x — the 192-wide B tile makes any prefetch state too large.
// Do not re-attempt pipelining here.
// ---------------------------------------------------------------------------
__global__ __launch_bounds__(128) void conv1_gemm_v5(const float* __restrict__ x,
                                                     const float* __restrict__ B,
                                                     int n, float* __restrict__ yz,
                                                     float* __restrict__ base,
                                                     const float* __restrict__ b1) {
    __shared__ __align__(16) float As[16][36];
    __shared__ __align__(16) float Bs[16][200];
    const int t = threadIdx.x;
    const int row0 = blockIdx.x * 32;
    const int ty = t >> 4, tx = t & 15;
    const int arow = t >> 2, alk = (t & 3) << 2;
    const int bkk0 = t >> 4, bcol = (t & 15) << 2;
    float acc[4][12];
    #pragma unroll
    for (int i = 0; i < 4; ++i)
        #pragma unroll
        for (int j = 0; j < 12; ++j) acc[i][j] = 0.f;

    for (int kt = 0; kt < 16; ++kt) {
        int k0 = kt << 4;
        {
            float4 av = make_float4(0.f, 0.f, 0.f, 0.f);
            int r = row0 + arow;
            if (r < n)
                av = *reinterpret_cast<const float4*>(&x[(size_t)r * 256 + k0 + alk]);
            As[alk + 0][arow] = av.x; As[alk + 1][arow] = av.y;
            As[alk + 2][arow] = av.z; As[alk + 3][arow] = av.w;
        }
        #pragma unroll
        for (int hh = 0; hh < 2; ++hh) {
            int kk = bkk0 + 8 * hh;
            const float* bp = &B[(size_t)(k0 + kk) * 192 + bcol];
            *reinterpret_cast<float4*>(&Bs[kk][bcol])       = *reinterpret_cast<const float4*>(bp);
            *reinterpret_cast<float4*>(&Bs[kk][bcol + 64])  = *reinterpret_cast<const float4*>(bp + 64);
            *reinterpret_cast<float4*>(&Bs[kk][bcol + 128]) = *reinterpret_cast<const float4*>(bp + 128);
        }
        __syncthreads();
        #pragma unroll
        for (int kk = 0; kk < 16; ++kk) {
            float4 a0 = *reinterpret_cast<const float4*>(&As[kk][ty << 2]);
            float4 b0 = *reinterpret_cast<const float4*>(&Bs[kk][tx << 2]);
            float4 b1q = *reinterpret_cast<const float4*>(&Bs[kk][(tx << 2) + 64]);
            float4 b2q = *reinterpret_cast<const float4*>(&Bs[kk][(tx << 2) + 128]);
            float aa[4] = {a0.x, a0.y, a0.z, a0.w};
            float bb[12] = {b0.x, b0.y, b0.z, b0.w, b1q.x, b1q.y, b1q.z, b1q.w,
                            b2q.x, b2q.y, b2q.z, b2q.w};
            #pragma unroll
            for (int i = 0; i < 4; ++i)
                #pragma unroll
                for (int j = 0; j < 12; ++j)
                    acc[i][j] = fmaf(aa[i], bb[j], acc[i][j]);
        }
        __syncthreads();
    }

    float4 bb4 = *reinterpret_cast<const float4*>(&b1[tx << 2]);
    #pragma unroll
    for (int i = 0; i < 4; ++i) {
        int r = row0 + (ty << 2) + i;
        if (r >= n) continue;
        float4 q0 = make_float4(acc[i][0], acc[i][1], acc[i][2], acc[i][3]);
        float4 q1 = make_float4(acc[i][4], acc[i][5], acc[i][6], acc[i][7]);
        float4 q2 = make_float4(acc[i][8] + bb4.x, acc[i][9] + bb4.y,
                                acc[i][10] + bb4.z, acc[i][11] + bb4.w);
        *reinterpret_cast<float4*>(&yz[(size_t)r * 128 + (tx << 2)]) = q0;
        *reinterpret_cast<float4*>(&yz[(size_t)r * 128 + 64 + (tx << 2)]) = q1;
        *reinterpret_cast<float4*>(&base[(size_t)r * 64 + (tx << 2)]) = q2;
    }
}

// ---------------------------------------------------------------------------
// conv1 edge transform (8 lanes/node x 8 ch) — R5 form (line-coalesced:
// 8 lanes cover the full 64-ch y row and z row; 512B/edge fully used).
// ---------------------------------------------------------------------------
__global__ __launch_bounds__(256) void edge_tf64_v8(const float* __restrict__ yz,
                                                    const int* __restrict__ rowp,
                                                    const int2* __restrict__ epk,
                                                    const float* __restrict__ invd,
                                                    const float* __restrict__ base,
                                                    float* __restrict__ out, int n) {
    int gid = blockIdx.x * 256 + threadIdx.x;
    int node = gid >> 3;
    if (node >= n) return;
    int c8 = (gid & 7) << 3;
    int e = rowp[node], eend = rowp[node + 1];
    float a[8] = {0.f, 0.f, 0.f, 0.f, 0.f, 0.f, 0.f, 0.f};
    for (; e + 2 <= eend; e += 2) {
        int2 q0 = epk[e], q1 = epk[e + 1];
        int s0 = q0.x, s1 = q1.x;
        float p0 = __int_as_float(q0.y), p1 = __int_as_float(q1.y);
        float4 y0a = *reinterpret_cast<const float4*>(&yz[(size_t)s0 * 128 + c8]);
        float4 y0b = *reinterpret_cast<const float4*>(&yz[(size_t)s0 * 128 + c8 + 4]);
        float4 z0a = *reinterpret_cast<const float4*>(&yz[(size_t)s0 * 128 + 64 + c8]);
        float4 z0b = *reinterpret_cast<const float4*>(&yz[(size_t)s0 * 128 + 64 + c8 + 4]);
        float4 y1a = *reinterpret_cast<const float4*>(&yz[(size_t)s1 * 128 + c8]);
        float4 y1b = *reinterpret_cast<const float4*>(&yz[(size_t)s1 * 128 + c8 + 4]);
        float4 z1a = *reinterpret_cast<const float4*>(&yz[(size_t)s1 * 128 + 64 + c8]);
        float4 z1b = *reinterpret_cast<const float4*>(&yz[(size_t)s1 * 128 + 64 + c8 + 4]);
        const float* ya0 = &y0a.x; const float* yb0 = &y0b.x;
        const float* za0 = &z0a.x; const float* zb0 = &z0b.x;
        const float* ya1 = &y1a.x; const float* yb1 = &y1b.x;
        const float* za1 = &z1a.x; const float* zb1 = &z1b.x;
        #pragma unroll
        for (int j = 0; j < 4; ++j) {
            a[j]     += fmaf(p0, za0[j] - ya0[j], ya0[j]) + fmaf(p1, za1[j] - ya1[j], ya1[j]);
            a[4 + j] += fmaf(p0, zb0[j] - yb0[j], yb0[j]) + fmaf(p1, zb1[j] - yb1[j], yb1[j]);
        }
    }
    for (; e < eend; ++e) {
        int2 q = epk[e];
        int s = q.x;
        float pe = __int_as_float(q.y);
        float4 ya = *reinterpret_cast<const float4*>(&yz[(size_t)s * 128 + c8]);
        float4 yb = *reinterpret_cast<const float4*>(&yz[(size_t)s * 128 + c8 + 4]);
        float4 za = *reinterpret_cast<const float4*>(&yz[(size_t)s * 128 + 64 + c8]);
        float4 zb = *reinterpret_cast<const float4*>(&yz[(size_t)s * 128 + 64 + c8 + 4]);
        const float* fy = &ya.x; const float* gy = &yb.x;
        const float* fz = &za.x; const float* gz = &zb.x;
        #pragma unroll
        for (int j = 0; j < 4; ++j) {
            a[j]     += fmaf(pe, fz[j] - fy[j], fy[j]);
            a[4 + j] += fmaf(pe, gz[j] - gy[j], gy[j]);
        }
    }
    float w = invd[node];
    size_t idx = (size_t)node * 64 + c8;
    float4 ba = *reinterpret_cast<const float4*>(&base[idx]);
    float4 bbv = *reinterpret_cast<const float4*>(&base[idx + 4]);
    float4 o0 = make_float4(tanhf(fmaf(a[0], w, ba.x)), tanhf(fmaf(a[1], w, ba.y)),
                            tanhf(fmaf(a[2], w, ba.z)), tanhf(fmaf(a[3], w, ba.w)));
    float4 o1 = make_float4(tanhf(fmaf(a[4], w, bbv.x)), tanhf(fmaf(a[5], w, bbv.y)),
                            tanhf(fmaf(a[6], w, bbv.z)), tanhf(fmaf(a[7], w, bbv.w)));
    *reinterpret_cast<float4*>(&out[idx]) = o0;
    *reinterpret_cast<float4*>(&out[idx + 4]) = o1;
}

__global__ __launch_bounds__(256) void edge_tf16_lsm(const float* __restrict__ yz,
                                                     const int* __restrict__ rowp,
                                                     const int2* __restrict__ epk,
                                                     const float* __restrict__ invd,
                                                     const float* __restrict__ base,
                                                     float* __restrict__ out, int n) {
    int gid = blockIdx.x * 256 + threadIdx.x;
    int node = gid >> 4;
    if (node >= n) return;
    int c = gid & 15;
    int e = rowp[node], eend = rowp[node + 1];
    float a = 0.f;
    for (; e + 4 <= eend; e += 4) {
        int2 q0 = epk[e], q1 = epk[e + 1], q2 = epk[e + 2], q3 = epk[e + 3];
        int s0 = q0.x, s1 = q1.x, s2 = q2.x, s3 = q3.x;
        float p0 = __int_as_float(q0.y), p1 = __int_as_float(q1.y);
        float p2 = __int_as_float(q2.y), p3 = __int_as_float(q3.y);
        float y0 = yz[(size_t)s0 * 32 + c],      z0 = yz[(size_t)s0 * 32 + 16 + c];
        float y1 = yz[(size_t)s1 * 32 + c],      z1 = yz[(size_t)s1 * 32 + 16 + c];
        float y2 = yz[(size_t)s2 * 32 + c],      z2 = yz[(size_t)s2 * 32 + 16 + c];
        float y3 = yz[(size_t)s3 * 32 + c],      z3 = yz[(size_t)s3 * 32 + 16 + c];
        a += fmaf(p0, z0 - y0, y0);
        a += fmaf(p1, z1 - y1, y1);
        a += fmaf(p2, z2 - y2, y2);
        a += fmaf(p3, z3 - y3, y3);
    }
    for (; e < eend; ++e) {
        int2 q = epk[e];
        int s = q.x; float pe = __int_as_float(q.y);
        float y = yz[(size_t)s * 32 + c], z = yz[(size_t)s * 32 + 16 + c];
        a += fmaf(pe, z - y, y);
    }
    float o = tanhf(a * invd[node] + base[(size_t)node * 16 + c]);
    float m = o;
    #pragma unroll
    for (int off = 8; off >= 1; off >>= 1) m = fmaxf(m, __shfl_xor(m, off, 16));
    float ex = expf(o - m);
    float s = ex;
    #pragma unroll
    for (int off = 8; off >= 1; off >>= 1) s += __shfl_xor(s, off, 16);
    out[(size_t)node * 16 + c] = (o - m) - logf(s);
}

// ---------------------------------------------------------------------------
// conv2 GEMM (K=64, M=48)
// ---------------------------------------------------------------------------
__global__ __launch_bounds__(256) void gemm_tiled(
    const float* __restrict__ A0, int lda0, int K0,
    const float* __restrict__ A1, int lda1,
    const float* __restrict__ B,
    int n, int K, int M,
    float* __restrict__ out0, int w0, const float* __restrict__ bias0,
    float* __restrict__ out1, int w1, const float* __restrict__ bias1,
    int split) {
    __shared__ __align__(16) float As[16][68];
    __shared__ __align__(16) float Bs[16][68];
    const int t = threadIdx.x;
    const int row0 = blockIdx.x * 64;
    const int col0 = blockIdx.y * 64;
    const int ty = t >> 4, tx = t & 15;
    const int lrow = t >> 2, lk = (t & 3) << 2;
    const int bkk = t >> 4, bcol = (t & 15) << 2;
    float acc[4][4];
    #pragma unroll
    for (int i = 0; i < 4; ++i)
        #pragma unroll
        for (int j = 0; j < 4; ++j) acc[i][j] = 0.f;

    for (int k0 = 0; k0 < K; k0 += 16) {
        float4 av = make_float4(0.f, 0.f, 0.f, 0.f);
        {
            int r = row0 + lrow;
            if (r < n) {
                int kk = k0 + lk;
                const float* src = (kk < K0)
                    ? (A0 + (size_t)r * lda0 + kk)
                    : (A1 + (size_t)r * lda1 + (kk - K0));
                av = *reinterpret_cast<const float4*>(src);
            }
        }
        float4 bv = make_float4(0.f, 0.f, 0.f, 0.f);
        {
            int c = col0 + bcol;
            int kk = k0 + bkk;
            if (c < M) bv = *reinterpret_cast<const float4*>(B + (size_t)kk * M + c);
        }
        As[lk + 0][lrow] = av.x; As[lk + 1][lrow] = av.y;
        As[lk + 2][lrow] = av.z; As[lk + 3][lrow] = av.w;
        *reinterpret_cast<float4*>(&Bs[bkk][bcol]) = bv;
        __syncthreads();
        #pragma unroll
        for (int kk = 0; kk < 16; ++kk) {
            float4 a4 = *reinterpret_cast<const float4*>(&As[kk][ty << 2]);
            float4 b4 = *reinterpret_cast<const float4*>(&Bs[kk][tx << 2]);
            float aa[4] = {a4.x, a4.y, a4.z, a4.w};
            float bb[4] = {b4.x, b4.y, b4.z, b4.w};
            #pragma unroll
            for (int i = 0; i < 4; ++i)
                #pragma unroll
                for (int j = 0; j < 4; ++j)
                    acc[i][j] = fmaf(aa[i], bb[j], acc[i][j]);
        }
        __syncthreads();
    }

    #pragma unroll
    for (int i = 0; i < 4; ++i) {
        int r = row0 + (ty << 2) + i;
        if (r >= n) continue;
        #pragma unroll
        for (int j = 0; j < 4; ++j) {
            int c = col0 + (tx << 2) + j;
            if (c >= M) continue;
            float v = acc[i][j];
            if (c < split) {
                if (bias0) v += bias0[c];
                out0[(size_t)r * w0 + c] = v;
            } else {
                int cc = c - split;
                if (bias1) v += bias1[cc];
                out1[(size_t)r * w1 + cc] = v;
            }
        }
    }
}

// ---------------------------------------------------------------------------
// Host-side launcher
// ---------------------------------------------------------------------------

static void hidden_conv(hipStream_t stream, const float* in, float* agg,
                        const int* rowp, const int2* epk,
                        const float* invd, const float* Bc, const float* bias, int n,
                        int mode, float* u_out,
                        const float* h, const float* acc_in, float* acc_out,
                        float* t_out, float c1, float c2, float c3) {
    edge_agg64_v5<<<ceil_div(n * 16, 256), 256, 0, stream>>>(in, rowp, epk, invd,
                                                             agg, n);
    hidden_gemm_48<<<ceil_div(n, 64), 128, 0, stream>>>(agg, in, Bc, bias, n, mode,
                                                        u_out, h, acc_in, acc_out,
                                                        t_out, c1, c2, c3);
}

extern "C" void kernel_launch(void* const* d_in, const int* in_sizes, int n_in,
                              void* d_out, int out_size, void* d_ws, size_t ws_size,
                              hipStream_t stream) {
    const float* x  = (const float*)d_in[0];
    const float* pE = (const float*)d_in[1];
    const int*   sr = (const int*)d_in[2];
    const int*   ds = (const int*)d_in[3];
    const float* W1 = (const float*)d_in[4];
    const float* R1 = (const float*)d_in[5];
    const float* b1 = (const float*)d_in[6];
    const float* Wa = (const float*)d_in[7];
    const float* Ra = (const float*)d_in[8];
    const float* ba = (const float*)d_in[9];
    const float* Wb = (const float*)d_in[10];
    const float* Rb = (const float*)d_in[11];
    const float* bb = (const float*)d_in[12];
    const float* W2 = (const float*)d_in[13];
    const float* R2 = (const float*)d_in[14];
    const float* b2 = (const float*)d_in[15];
    const int n = in_sizes[0] / 256;
    const int E = in_sizes[2];
    float* out = (float*)d_out;

    char* w = (char*)d_ws;
    auto alloc = [&](size_t bytes) -> void* {
        void* ptr = (void*)w;
        w += (bytes + 255) & ~(size_t)255;
        return ptr;
    };
    int nscan = ceil_div(n, 2048);
    int*   deg  = (int*)alloc((size_t)n * 4);
    int*   fill = (int*)alloc((size_t)n * 4);
    int*   rowp = (int*)alloc((size_t)(n + 1) * 4);
    float* invd = (float*)alloc((size_t)n * 4);
    int*   bsum = (int*)alloc((size_t)256 * 4);
    int*   ei   = (int*)alloc((size_t)E * 4);
    int2*  epk  = (int2*)alloc((size_t)E * 8);
    float* Bc1  = (float*)alloc((size_t)256 * 192 * 4);
    float* Bca  = (float*)alloc((size_t)192 * 64 * 4);
    float* Bcb  = (float*)alloc((size_t)192 * 64 * 4);
    float* Bc2  = (float*)alloc((size_t)64 * 48 * 4);
    float* big0 = (float*)alloc((size_t)n * 128 * 4);  // yz / agg buffer
    float* big1 = (float*)alloc((size_t)n * 64 * 4);   // base buffer
    float* h    = (float*)alloc((size_t)n * 64 * 4);
    float* u    = (float*)alloc((size_t)n * 64 * 4);
    float* tb   = (float*)alloc((size_t)n * 64 * 4);
    float* acc  = (float*)alloc((size_t)n * 64 * 4);

    const int PACK_TOTAL = 256 * 192 + 2 * 192 * 64 + 64 * 48;

    zero2<<<ceil_div(n, 256), 256, 0, stream>>>(deg, fill, n);
    pack_all<<<ceil_div(PACK_TOTAL, 256), 256, 0, stream>>>(W1, R1, Wa, Ra, Wb, Rb,
                                                            W2, R2, Bc1, Bca, Bcb, Bc2);
    hist_kernel<<<ceil_div(E, 256), 256, 0, stream>>>(ds, deg, E);
    scan_blocksum<<<nscan, 256, 0, stream>>>(deg, bsum, n);
    scan_tops<<<1, 256, 0, stream>>>(bsum, nscan);
    scan_final<<<nscan, 256, 0, stream>>>(deg, bsum, rowp, invd, n, E);
    scatter_idx<<<ceil_div(E, 256), 256, 0, stream>>>(ds, rowp, fill, ei, E);
    sort_fill<<<ceil_div(n, 256), 256, 0, stream>>>(rowp, ei, sr, pE, epk, n);

    // conv1: x @ [W1_0|W1_1|R1] -> yz(big0), base(big1)+b1; then edge transform
    conv1_gemm_v5<<<ceil_div(n, 32), 128, 0, stream>>>(x, Bc1, n, big0, big1, b1);
    edge_tf64_v8<<<ceil_div(n * 8, 256), 256, 0, stream>>>(big0, rowp, epk, invd,
                                                           big1, h, n);

    // RK4 over f(y) = conv_b(conv_a(y)), T=3
    // k1
    hidden_conv(stream, h, big0, rowp, epk, invd, Bca, ba, n, 0, u,
                nullptr, nullptr, nullptr, nullptr, 0.f, 0.f, 0.f);
    hidden_conv(stream, u, big0, rowp, epk, invd, Bcb, bb, n, 1, nullptr,
                h, nullptr, acc, tb, 1.5f, 0.f, 1.f);
    // k2
    hidden_conv(stream, tb, big0, rowp, epk, invd, Bca, ba, n, 0, u,
                nullptr, nullptr, nullptr, nullptr, 0.f, 0.f, 0.f);
    hidden_conv(stream, u, big0, rowp, epk, invd, Bcb, bb, n, 1, nullptr,
                h, acc, acc, tb, 1.5f, 0.f, 2.f);
    // k3
    hidden_conv(stream, tb, big0, rowp, epk, invd, Bca, ba, n, 0, u,
                nullptr, nullptr, nullptr, nullptr, 0.f, 0.f, 0.f);
    hidden_conv(stream, u, big0, rowp, epk, invd, Bcb, bb, n, 1, nullptr,
                h, acc, acc, tb, 3.f, 0.f, 2.f);
    // k4: t_out becomes h_new = h + 0.5*(k1+2k2+2k3+k4)
    hidden_conv(stream, tb, big0, rowp, epk, invd, Bca, ba, n, 0, u,
                nullptr, nullptr, nullptr, nullptr, 0.f, 0.f, 0.f);
    hidden_conv(stream, u, big0, rowp, epk, invd, Bcb, bb, n, 1, nullptr,
                h, acc, acc, tb, 0.f, 0.5f, 1.f);

    // conv2: h_new @ [W2_0|W2_1|R2] -> yz2(big0,w=32), base2(big1,w=16)+b2
    gemm_tiled<<<dim3(ceil_div(n, 64), 1), 256, 0, stream>>>(
        tb, 64, 64, nullptr, 0, Bc2, n, 64, 48,
        big0, 32, nullptr, big1, 16, b2, 32);
    edge_tf16_lsm<<<ceil_div(n * 16, 256), 256, 0, stream>>>(big0, rowp, epk, invd,
                                                             big1, out, n);
}